// Round 1
// baseline (1876.052 us; speedup 1.0000x reference)
//
#include <hip/hip_runtime.h>

#define BATCH 4
#define NPTS  4096
#define INDIM 1024
#define EMB   512
#define ATT   128
#define KNN   8
#define NCLS  2

// ---------------------------------------------------------------------------
// Tiled fp32 GEMM:  C[M,Nc] = A[M,K] @ W[K,Nc] + bias[Nc]
// BM=64, BN=64, BK=16, 256 threads, 4x4 micro-tile per thread.
// ---------------------------------------------------------------------------
template<int K>
__global__ __launch_bounds__(256)
void gemm_bias(const float* __restrict__ A, const float* __restrict__ W,
               const float* __restrict__ bias, float* __restrict__ C, int Nc) {
    __shared__ float As[16][68];   // [k][m], padded
    __shared__ float Ws[16][68];   // [k][n], padded
    const int r0 = blockIdx.y * 64;
    const int c0 = blockIdx.x * 64;
    const int t  = threadIdx.x;
    const int tx = t & 15, ty = t >> 4;
    const int lrow = t >> 2, lkc = (t & 3) * 4;   // A-tile stage: 64 rows x 16 k
    const int wkk  = t >> 4, wcc = (t & 15) * 4;  // W-tile stage: 16 k x 64 n
    float acc[4][4] = {};
    for (int k0 = 0; k0 < K; k0 += 16) {
        const float4 a4 = *(const float4*)&A[(size_t)(r0 + lrow) * K + k0 + lkc];
        As[lkc + 0][lrow] = a4.x;
        As[lkc + 1][lrow] = a4.y;
        As[lkc + 2][lrow] = a4.z;
        As[lkc + 3][lrow] = a4.w;
        *(float4*)&Ws[wkk][wcc] = *(const float4*)&W[(size_t)(k0 + wkk) * Nc + c0 + wcc];
        __syncthreads();
        #pragma unroll
        for (int k = 0; k < 16; ++k) {
            const float4 a = *(const float4*)&As[k][ty * 4];
            const float4 b = *(const float4*)&Ws[k][tx * 4];
            const float a_[4] = {a.x, a.y, a.z, a.w};
            const float b_[4] = {b.x, b.y, b.z, b.w};
            #pragma unroll
            for (int i = 0; i < 4; ++i)
                #pragma unroll
                for (int j = 0; j < 4; ++j)
                    acc[i][j] = fmaf(a_[i], b_[j], acc[i][j]);
        }
        __syncthreads();
    }
    const float4 b4 = *(const float4*)&bias[c0 + tx * 4];
    #pragma unroll
    for (int i = 0; i < 4; ++i) {
        float4 o;
        o.x = acc[i][0] + b4.x;
        o.y = acc[i][1] + b4.y;
        o.z = acc[i][2] + b4.z;
        o.w = acc[i][3] + b4.w;
        *(float4*)&C[(size_t)(r0 + ty * 4 + i) * Nc + c0 + tx * 4] = o;
    }
}

// ---------------------------------------------------------------------------
// Row inverse-norms: rnorm[i] = 1/max(||h_i||, 1e-12), rows of length 512.
// ---------------------------------------------------------------------------
__global__ __launch_bounds__(64)
void rownorm_kernel(const float* __restrict__ h, float* __restrict__ rnorm) {
    const int row  = blockIdx.x;
    const int lane = threadIdx.x;
    float ss = 0.0f;
    #pragma unroll
    for (int i = 0; i < 2; ++i) {
        const float4 v = *(const float4*)&h[(size_t)row * EMB + lane * 8 + i * 4];
        ss += v.x * v.x + v.y * v.y + v.z * v.z + v.w * v.w;
    }
    #pragma unroll
    for (int o = 32; o > 0; o >>= 1) ss += __shfl_xor(ss, o);
    if (lane == 0) rnorm[row] = 1.0f / fmaxf(sqrtf(ss), 1e-12f);
}

// ---------------------------------------------------------------------------
// Fused cosine-sim GEMM + running top-8 per row (partial over a column range).
// Grid: (64 row-blocks, 4 column-parts, 4 batches). Block: 256 threads.
// Each part covers 1024 columns; partial top-8 (val,idx) written per row/part.
// ---------------------------------------------------------------------------
__global__ __launch_bounds__(256)
void simtopk_part(const float* __restrict__ h, const float* __restrict__ rnorm,
                  float* __restrict__ ptv, int* __restrict__ pti) {
    const int rb   = blockIdx.x;
    const int part = blockIdx.y;
    const int b    = blockIdx.z;
    const int r0   = rb * 64;
    const float* hb = h + (size_t)b * NPTS * EMB;
    const float* rn = rnorm + b * NPTS;

    __shared__ float As[32][68];
    __shared__ float Bs[32][68];
    __shared__ float simbuf[64][68];

    const int t  = threadIdx.x;
    const int tx = t & 15, ty = t >> 4;
    const int lrow = t >> 2, lkc = (t & 3) * 4;
    const float sA = rn[r0 + lrow];

    float tv[8]; int ti[8];
    #pragma unroll
    for (int j = 0; j < 8; ++j) { tv[j] = -2.0f; ti[j] = 0; }
    float minv = -2.0f; int minp = 0;

    for (int cb = part * 16; cb < part * 16 + 16; ++cb) {
        const int c0 = cb * 64;
        const float sB = rn[c0 + lrow];
        float acc[4][4] = {};
        for (int k0 = 0; k0 < EMB; k0 += 32) {
            #pragma unroll
            for (int kh = 0; kh < 32; kh += 16) {
                const float4 a4 = *(const float4*)&hb[(size_t)(r0 + lrow) * EMB + k0 + kh + lkc];
                As[kh + lkc + 0][lrow] = a4.x * sA;
                As[kh + lkc + 1][lrow] = a4.y * sA;
                As[kh + lkc + 2][lrow] = a4.z * sA;
                As[kh + lkc + 3][lrow] = a4.w * sA;
                const float4 b4 = *(const float4*)&hb[(size_t)(c0 + lrow) * EMB + k0 + kh + lkc];
                Bs[kh + lkc + 0][lrow] = b4.x * sB;
                Bs[kh + lkc + 1][lrow] = b4.y * sB;
                Bs[kh + lkc + 2][lrow] = b4.z * sB;
                Bs[kh + lkc + 3][lrow] = b4.w * sB;
            }
            __syncthreads();
            #pragma unroll
            for (int k = 0; k < 32; ++k) {
                const float4 a = *(const float4*)&As[k][ty * 4];
                const float4 b = *(const float4*)&Bs[k][tx * 4];
                const float a_[4] = {a.x, a.y, a.z, a.w};
                const float b_[4] = {b.x, b.y, b.z, b.w};
                #pragma unroll
                for (int i = 0; i < 4; ++i)
                    #pragma unroll
                    for (int j = 0; j < 4; ++j)
                        acc[i][j] = fmaf(a_[i], b_[j], acc[i][j]);
            }
            __syncthreads();
        }
        #pragma unroll
        for (int i = 0; i < 4; ++i)
            *(float4*)&simbuf[ty * 4 + i][tx * 4] =
                make_float4(acc[i][0], acc[i][1], acc[i][2], acc[i][3]);
        __syncthreads();
        if (t < 64) {
            const int grow = r0 + t;
            for (int cc = 0; cc < 64; ++cc) {
                const int c  = (cc + t) & 63;   // rotated start: avoids bank conflicts
                const int gc = c0 + c;
                const float v = simbuf[t][c];
                if (gc != grow && v > minv) {
                    tv[minp] = v; ti[minp] = gc;
                    minv = tv[0]; minp = 0;
                    #pragma unroll
                    for (int j = 1; j < 8; ++j)
                        if (tv[j] < minv) { minv = tv[j]; minp = j; }
                }
            }
        }
        __syncthreads();
    }
    if (t < 64) {
        const size_t base = ((size_t)(b * NPTS + r0 + t) * 4 + part) * 8;
        #pragma unroll
        for (int j = 0; j < 8; ++j) { ptv[base + j] = tv[j]; pti[base + j] = ti[j]; }
    }
}

// ---------------------------------------------------------------------------
// Merge 4 partial top-8 lists -> global top-8, softmax -> weights + indices.
// One thread per row.
// ---------------------------------------------------------------------------
__global__ __launch_bounds__(256)
void topk_merge(const float* __restrict__ ptv, const int* __restrict__ pti,
                float* __restrict__ tw, int* __restrict__ tidx) {
    const int row = blockIdx.x * 256 + threadIdx.x;   // 0..16383
    float tv[8]; int ti[8];
    #pragma unroll
    for (int j = 0; j < 8; ++j) { tv[j] = -2.0f; ti[j] = 0; }
    float minv = -2.0f; int minp = 0;
    for (int c = 0; c < 32; ++c) {
        const float v = ptv[(size_t)row * 32 + c];
        const int   g = pti[(size_t)row * 32 + c];
        if (v > minv) {
            tv[minp] = v; ti[minp] = g;
            minv = tv[0]; minp = 0;
            #pragma unroll
            for (int j = 1; j < 8; ++j)
                if (tv[j] < minv) { minv = tv[j]; minp = j; }
        }
    }
    float m = tv[0];
    #pragma unroll
    for (int j = 1; j < 8; ++j) m = fmaxf(m, tv[j]);
    float e[8], Z = 0.0f;
    #pragma unroll
    for (int j = 0; j < 8; ++j) { e[j] = __expf(tv[j] - m); Z += e[j]; }
    const float inv = 1.0f / Z;
    #pragma unroll
    for (int j = 0; j < 8; ++j) {
        tw[(size_t)row * 8 + j]   = e[j] * inv;
        tidx[(size_t)row * 8 + j] = ti[j];
    }
}

// ---------------------------------------------------------------------------
// h <- LayerNorm(h[row] + sum_j w_j * V[idx_j])   (in-place over h)
// One block (128 threads) per row; each thread owns 4 dims.
// ---------------------------------------------------------------------------
__global__ __launch_bounds__(128)
void agg_ln(float* hio, const float* __restrict__ V,
            const int* __restrict__ tidx, const float* __restrict__ tw,
            const float* __restrict__ g, const float* __restrict__ be) {
    const int row = blockIdx.x;
    const int b   = row >> 12;
    const float* Vb = V + (size_t)b * NPTS * EMB;
    const int t = threadIdx.x;
    const int e = t * 4;
    float4 acc = *(const float4*)&hio[(size_t)row * EMB + e];
    #pragma unroll
    for (int j = 0; j < 8; ++j) {
        const int   idx = tidx[(size_t)row * 8 + j];
        const float w   = tw[(size_t)row * 8 + j];
        const float4 v  = *(const float4*)&Vb[(size_t)idx * EMB + e];
        acc.x = fmaf(w, v.x, acc.x);
        acc.y = fmaf(w, v.y, acc.y);
        acc.z = fmaf(w, v.z, acc.z);
        acc.w = fmaf(w, v.w, acc.w);
    }
    float s  = acc.x + acc.y + acc.z + acc.w;
    float ss = acc.x * acc.x + acc.y * acc.y + acc.z * acc.z + acc.w * acc.w;
    #pragma unroll
    for (int o = 32; o > 0; o >>= 1) { s += __shfl_xor(s, o); ss += __shfl_xor(ss, o); }
    __shared__ float red[4];
    if ((t & 63) == 0) { red[(t >> 6) * 2] = s; red[(t >> 6) * 2 + 1] = ss; }
    __syncthreads();
    s  = red[0] + red[2];
    ss = red[1] + red[3];
    const float mu   = s * (1.0f / EMB);
    const float var  = ss * (1.0f / EMB) - mu * mu;
    const float rstd = rsqrtf(var + 1e-5f);
    const float4 gg = *(const float4*)&g[e];
    const float4 bb = *(const float4*)&be[e];
    float4 o4;
    o4.x = (acc.x - mu) * rstd * gg.x + bb.x;
    o4.y = (acc.y - mu) * rstd * gg.y + bb.y;
    o4.z = (acc.z - mu) * rstd * gg.z + bb.z;
    o4.w = (acc.w - mu) * rstd * gg.w + bb.w;
    *(float4*)&hio[(size_t)row * EMB + e] = o4;
}

// ---------------------------------------------------------------------------
// score[row] = sum_a tanh(AV[row,a]) * sigmoid(AU[row,a]) * aw_w[a] + aw_b
// One wave per row (4 rows per 256-thread block).
// ---------------------------------------------------------------------------
__global__ __launch_bounds__(256)
void score_kernel(const float* __restrict__ AV, const float* __restrict__ AU,
                  const float* __restrict__ aw_w, const float* __restrict__ aw_b,
                  float* __restrict__ score) {
    const int t    = threadIdx.x;
    const int row  = blockIdx.x * 4 + (t >> 6);
    const int lane = t & 63;
    float sum = 0.0f;
    #pragma unroll
    for (int i = 0; i < 2; ++i) {
        const int a = lane + i * 64;
        const float v = tanhf(AV[(size_t)row * ATT + a]);
        const float u = 1.0f / (1.0f + __expf(-AU[(size_t)row * ATT + a]));
        sum = fmaf(v * u, aw_w[a], sum);
    }
    #pragma unroll
    for (int o = 32; o > 0; o >>= 1) sum += __shfl_xor(sum, o);
    if (lane == 0) score[row] = sum + aw_b[0];
}

// ---------------------------------------------------------------------------
// Per-batch softmax over N scores; also zero the bag accumulator.
// ---------------------------------------------------------------------------
__global__ __launch_bounds__(256)
void softmax_kernel(const float* __restrict__ score, float* __restrict__ A,
                    float* __restrict__ bag) {
    const int b = blockIdx.x;
    const int t = threadIdx.x;
    const float* sb = score + b * NPTS;
    float loc[16];
    float m = -1e30f;
    #pragma unroll
    for (int i = 0; i < 16; ++i) { loc[i] = sb[t + i * 256]; m = fmaxf(m, loc[i]); }
    #pragma unroll
    for (int o = 32; o > 0; o >>= 1) m = fmaxf(m, __shfl_xor(m, o));
    __shared__ float redm[4];
    __shared__ float redz[4];
    if ((t & 63) == 0) redm[t >> 6] = m;
    __syncthreads();
    m = fmaxf(fmaxf(redm[0], redm[1]), fmaxf(redm[2], redm[3]));
    float Z = 0.0f;
    #pragma unroll
    for (int i = 0; i < 16; ++i) { loc[i] = __expf(loc[i] - m); Z += loc[i]; }
    #pragma unroll
    for (int o = 32; o > 0; o >>= 1) Z += __shfl_xor(Z, o);
    if ((t & 63) == 0) redz[t >> 6] = Z;
    __syncthreads();
    Z = redz[0] + redz[1] + redz[2] + redz[3];
    const float inv = 1.0f / Z;
    #pragma unroll
    for (int i = 0; i < 16; ++i) A[b * NPTS + t + i * 256] = loc[i] * inv;
    bag[b * EMB + t]       = 0.0f;
    bag[b * EMB + t + 256] = 0.0f;
}

// ---------------------------------------------------------------------------
// Partial weighted pooling: bag[b,e] += sum_{n in slice} A[b,n] * h2[b,n,e]
// Grid (16 slices, 4 batches), 512 threads (one per dim).
// ---------------------------------------------------------------------------
__global__ __launch_bounds__(512)
void bagpart_kernel(const float* __restrict__ A, const float* __restrict__ h2,
                    float* __restrict__ bag) {
    const int b = blockIdx.y;
    const int s = blockIdx.x;
    const int e = threadIdx.x;
    const int n0 = s * 256;
    float acc = 0.0f;
    for (int n = 0; n < 256; ++n) {
        const float a = A[b * NPTS + n0 + n];
        acc = fmaf(a, h2[(size_t)(b * NPTS + n0 + n) * EMB + e], acc);
    }
    atomicAdd(&bag[b * EMB + e], acc);
}

// ---------------------------------------------------------------------------
// logits[b,c] = bag[b,:] . cls_w[:,c] + cls_b[c].  One wave per output.
// ---------------------------------------------------------------------------
__global__ __launch_bounds__(512)
void logits_kernel(const float* __restrict__ bag, const float* __restrict__ cls_w,
                   const float* __restrict__ cls_b, float* __restrict__ out) {
    const int t    = threadIdx.x;
    const int w    = t >> 6;       // 0..7
    const int lane = t & 63;
    const int b = w >> 1, c = w & 1;
    float sum = 0.0f;
    #pragma unroll
    for (int i = 0; i < 8; ++i) {
        const int e = lane + i * 64;
        sum = fmaf(bag[b * EMB + e], cls_w[e * NCLS + c], sum);
    }
    #pragma unroll
    for (int o = 32; o > 0; o >>= 1) sum += __shfl_xor(sum, o);
    if (lane == 0) out[b * NCLS + c] = sum + cls_b[c];
}

// ---------------------------------------------------------------------------
extern "C" void kernel_launch(void* const* d_in, const int* in_sizes, int n_in,
                              void* d_out, int out_size, void* d_ws, size_t ws_size,
                              hipStream_t stream) {
    const float* x     = (const float*)d_in[0];
    const float* pe_w  = (const float*)d_in[1];
    const float* pe_b  = (const float*)d_in[2];
    const float* wv_w  = (const float*)d_in[3];
    const float* wv_b  = (const float*)d_in[4];
    const float* ln_g  = (const float*)d_in[5];
    const float* ln_b  = (const float*)d_in[6];
    const float* av_w  = (const float*)d_in[7];
    const float* av_b  = (const float*)d_in[8];
    const float* au_w  = (const float*)d_in[9];
    const float* au_b  = (const float*)d_in[10];
    const float* aw_w  = (const float*)d_in[11];
    const float* aw_b  = (const float*)d_in[12];
    const float* cls_w = (const float*)d_in[13];
    const float* cls_b = (const float*)d_in[14];

    char* ws = (char*)d_ws;
    // Layout (bytes). h is reused in-place as h2 after agg_ln; AV/AU reuse V.
    float* h     = (float*)(ws + 0);           // 16384x512 f32 = 33.5 MB (h, then h2)
    float* V     = (float*)(ws + 33554432);    // 33.5 MB (V, then AV/AU)
    float* rnorm = (float*)(ws + 67108864);    // 64 KB
    int*   tidx  = (int*)  (ws + 67174400);    // 512 KB
    float* tw    = (float*)(ws + 67698688);    // 512 KB
    float* scoreb= (float*)(ws + 68222976);    // 64 KB
    float* Asm   = (float*)(ws + 68288512);    // 64 KB
    float* bag   = (float*)(ws + 68354048);    // 8 KB
    float* ptv   = (float*)(ws + 68362240);    // 2 MB  partial topk vals
    int*   pti   = (int*)  (ws + 70459392);    // 2 MB  partial topk idx
    float* AV    = V;                          // reuse (V dead after agg_ln)
    float* AU    = (float*)(ws + 33554432 + 16777216);

    const int M = BATCH * NPTS;  // 16384

    // 1) h = x @ pe_w + pe_b
    gemm_bias<INDIM><<<dim3(EMB / 64, M / 64), dim3(256), 0, stream>>>(x, pe_w, pe_b, h, EMB);
    // 2) row inverse norms
    rownorm_kernel<<<dim3(M), dim3(64), 0, stream>>>(h, rnorm);
    // 3) V = h @ wv_w + wv_b
    gemm_bias<EMB><<<dim3(EMB / 64, M / 64), dim3(256), 0, stream>>>(h, wv_w, wv_b, V, EMB);
    // 4) fused cosine-sim + partial top-8  (64 row-blocks x 4 col-parts x 4 batches)
    simtopk_part<<<dim3(NPTS / 64, 4, BATCH), dim3(256), 0, stream>>>(h, rnorm, ptv, pti);
    // 5) merge partials -> softmaxed weights + indices
    topk_merge<<<dim3(M / 256), dim3(256), 0, stream>>>(ptv, pti, tw, tidx);
    // 6) h <- LN(h + gather(V))   (in-place; h is now h2)
    agg_ln<<<dim3(M), dim3(128), 0, stream>>>(h, V, tidx, tw, ln_g, ln_b);
    // 7) AV/AU pre-activations
    gemm_bias<EMB><<<dim3(ATT / 64, M / 64), dim3(256), 0, stream>>>(h, av_w, av_b, AV, ATT);
    gemm_bias<EMB><<<dim3(ATT / 64, M / 64), dim3(256), 0, stream>>>(h, au_w, au_b, AU, ATT);
    // 8) gated-attention scores
    score_kernel<<<dim3(M / 4), dim3(256), 0, stream>>>(AV, AU, aw_w, aw_b, scoreb);
    // 9) per-batch softmax over N (+ zero bag)
    softmax_kernel<<<dim3(BATCH), dim3(256), 0, stream>>>(scoreb, Asm, bag);
    // 10) weighted pooling
    bagpart_kernel<<<dim3(16, BATCH), dim3(512), 0, stream>>>(Asm, h, bag);
    // 11) classifier
    logits_kernel<<<dim3(1), dim3(512), 0, stream>>>(bag, cls_w, cls_b, (float*)d_out);
}

// Round 4
// 1136.996 us; speedup vs baseline: 1.6500x; 1.6500x over previous
//
#include <hip/hip_runtime.h>

#define BATCH 4
#define NPTS  4096
#define INDIM 1024
#define EMB   512
#define ATT   128
#define KNN   8
#define NCLS  2

typedef __attribute__((ext_vector_type(8))) short bf16x8;
typedef __attribute__((ext_vector_type(4))) float f32x4;

// ---------------------------------------------------------------------------
// Tiled fp32 GEMM:  C[M,Nc] = A[M,K] @ W[K,Nc] + bias[Nc]
// ---------------------------------------------------------------------------
template<int K>
__global__ __launch_bounds__(256)
void gemm_bias(const float* __restrict__ A, const float* __restrict__ W,
               const float* __restrict__ bias, float* __restrict__ C, int Nc) {
    __shared__ float As[16][68];
    __shared__ float Ws[16][68];
    const int r0 = blockIdx.y * 64;
    const int c0 = blockIdx.x * 64;
    const int t  = threadIdx.x;
    const int tx = t & 15, ty = t >> 4;
    const int lrow = t >> 2, lkc = (t & 3) * 4;
    const int wkk  = t >> 4, wcc = (t & 15) * 4;
    float acc[4][4] = {};
    for (int k0 = 0; k0 < K; k0 += 16) {
        const float4 a4 = *(const float4*)&A[(size_t)(r0 + lrow) * K + k0 + lkc];
        As[lkc + 0][lrow] = a4.x;
        As[lkc + 1][lrow] = a4.y;
        As[lkc + 2][lrow] = a4.z;
        As[lkc + 3][lrow] = a4.w;
        *(float4*)&Ws[wkk][wcc] = *(const float4*)&W[(size_t)(k0 + wkk) * Nc + c0 + wcc];
        __syncthreads();
        #pragma unroll
        for (int k = 0; k < 16; ++k) {
            const float4 a = *(const float4*)&As[k][ty * 4];
            const float4 b = *(const float4*)&Ws[k][tx * 4];
            const float a_[4] = {a.x, a.y, a.z, a.w};
            const float b_[4] = {b.x, b.y, b.z, b.w};
            #pragma unroll
            for (int i = 0; i < 4; ++i)
                #pragma unroll
                for (int j = 0; j < 4; ++j)
                    acc[i][j] = fmaf(a_[i], b_[j], acc[i][j]);
        }
        __syncthreads();
    }
    const float4 b4 = *(const float4*)&bias[c0 + tx * 4];
    #pragma unroll
    for (int i = 0; i < 4; ++i) {
        float4 o;
        o.x = acc[i][0] + b4.x;
        o.y = acc[i][1] + b4.y;
        o.z = acc[i][2] + b4.z;
        o.w = acc[i][3] + b4.w;
        *(float4*)&C[(size_t)(r0 + ty * 4 + i) * Nc + c0 + tx * 4] = o;
    }
}

// ---------------------------------------------------------------------------
// Normalize rows of h (fp32) -> hn (bf16).  One 64-thread block per row.
// ---------------------------------------------------------------------------
__device__ __forceinline__ ushort f2bf(float x) {
    unsigned u = __float_as_uint(x);
    u += 0x7fff + ((u >> 16) & 1);   // RNE
    return (ushort)(u >> 16);
}

__global__ __launch_bounds__(64)
void normcast_kernel(const float* __restrict__ h, ushort* __restrict__ hn) {
    const int row  = blockIdx.x;
    const int lane = threadIdx.x;
    const float4 v0 = *(const float4*)&h[(size_t)row * EMB + lane * 8];
    const float4 v1 = *(const float4*)&h[(size_t)row * EMB + lane * 8 + 4];
    float ss = v0.x * v0.x + v0.y * v0.y + v0.z * v0.z + v0.w * v0.w
             + v1.x * v1.x + v1.y * v1.y + v1.z * v1.z + v1.w * v1.w;
    #pragma unroll
    for (int o = 32; o > 0; o >>= 1) ss += __shfl_xor(ss, o);
    const float rn = 1.0f / fmaxf(sqrtf(ss), 1e-12f);
    uint4 o4;
    o4.x = (unsigned)f2bf(v0.x * rn) | ((unsigned)f2bf(v0.y * rn) << 16);
    o4.y = (unsigned)f2bf(v0.z * rn) | ((unsigned)f2bf(v0.w * rn) << 16);
    o4.z = (unsigned)f2bf(v1.x * rn) | ((unsigned)f2bf(v1.y * rn) << 16);
    o4.w = (unsigned)f2bf(v1.z * rn) | ((unsigned)f2bf(v1.w * rn) << 16);
    *(uint4*)&hn[(size_t)row * EMB + lane * 8] = o4;
}

// ---------------------------------------------------------------------------
// MFMA cosine-sim + running top-8.  Block: 256 thr (4 waves), 64 rows,
// scans 1024 cols (part).  K-chunk 64, double-buffered, XOR-swizzled LDS.
// Partial top-8 per (row, part) -> ptv/pti, layout [row][4][8].
// ---------------------------------------------------------------------------
__global__ __launch_bounds__(256)
void simtopk_mfma(const ushort* __restrict__ hn,
                  float* __restrict__ ptv, int* __restrict__ pti) {
    const int rb = blockIdx.x, part = blockIdx.y, b = blockIdx.z;
    const int r0 = rb * 64;
    const ushort* hb = hn + (size_t)b * NPTS * EMB;

    __shared__ ushort As[2][4096];     // [64 rows][64 k] bf16, swizzled
    __shared__ ushort Bs[2][4096];
    __shared__ float  simbuf[64 * 65]; // pitch-65: conflict-free scan

    const int t    = threadIdx.x;
    const int wave = t >> 6;
    const int lane = t & 63;

    // staging map: piece q = t and q = 256+t; row = q>>3, kbyte = (q&7)*16
    const int q0row = t >> 3,        q0kb = (t & 7) * 16;
    const int q1row = 32 + (t >> 3), q1kb = q0kb;
    const int d0 = q0row * 64 + ((q0kb ^ ((q0row & 7) << 4)) >> 1); // ushort idx
    const int d1 = q1row * 64 + ((q1kb ^ ((q1row & 7) << 4)) >> 1);

    // fragment addressing
    const int arow = wave * 16 + (lane & 15);   // this wave's A row
    const int aswz = (arow & 7) << 4;
    const int g16  = (lane >> 4) * 16;          // k-group byte offset

    // scan mapping: 4 threads per row
    const int srow = t >> 2, ssub = t & 3;
    const int growg = r0 + srow;

    float tv[8]; int ti[8];
    #pragma unroll
    for (int j = 0; j < 8; ++j) { tv[j] = -2.0f; ti[j] = 0; }
    float minv = -2.0f; int minp = 0;

    uint4 rg[2][4];

    for (int cc = 0; cc < 16; ++cc) {
        const int c0 = part * 1024 + cc * 64;

        f32x4 acc[4];
        #pragma unroll
        for (int f = 0; f < 4; ++f) acc[f] = (f32x4){0.f, 0.f, 0.f, 0.f};

        #define GLOAD(set, k0)                                                        \
            rg[set][0] = *(const uint4*)&hb[(size_t)(r0 + q0row) * EMB + (k0) + (q0kb >> 1)]; \
            rg[set][1] = *(const uint4*)&hb[(size_t)(r0 + q1row) * EMB + (k0) + (q1kb >> 1)]; \
            rg[set][2] = *(const uint4*)&hb[(size_t)(c0 + q0row) * EMB + (k0) + (q0kb >> 1)]; \
            rg[set][3] = *(const uint4*)&hb[(size_t)(c0 + q1row) * EMB + (k0) + (q1kb >> 1)];
        #define SWRITE(buf, set)                          \
            *(uint4*)&As[buf][d0] = rg[set][0];           \
            *(uint4*)&As[buf][d1] = rg[set][1];           \
            *(uint4*)&Bs[buf][d0] = rg[set][2];           \
            *(uint4*)&Bs[buf][d1] = rg[set][3];

        GLOAD(0, 0)
        SWRITE(0, 0)
        GLOAD(1, 64)

        #pragma unroll
        for (int kc = 0; kc < 8; ++kc) {
            __syncthreads();                       // buf[kc&1] ready for all waves
            if (kc < 7) { SWRITE((kc + 1) & 1, (kc + 1) & 1) }
            if (kc < 6) { GLOAD(kc & 1, (kc + 2) * 64) }
            #pragma unroll
            for (int ks = 0; ks < 2; ++ks) {
                const int kb = ks * 64 + g16;
                const bf16x8 a = *(const bf16x8*)
                    ((const char*)&As[kc & 1][0] + arow * 128 + (kb ^ aswz));
                #pragma unroll
                for (int f = 0; f < 4; ++f) {
                    const int bcol = f * 16 + (lane & 15);
                    const bf16x8 bb = *(const bf16x8*)
                        ((const char*)&Bs[kc & 1][0] + bcol * 128 + (kb ^ ((bcol & 7) << 4)));
                    acc[f] = __builtin_amdgcn_mfma_f32_16x16x32_bf16(a, bb, acc[f], 0, 0, 0);
                }
            }
        }
        #undef GLOAD
        #undef SWRITE

        // drop sim tile to LDS (C-frag: col=lane&15, row=(lane>>4)*4+reg)
        #pragma unroll
        for (int f = 0; f < 4; ++f)
            #pragma unroll
            for (int r = 0; r < 4; ++r)
                simbuf[(wave * 16 + (lane >> 4) * 4 + r) * 65 + f * 16 + (lane & 15)]
                    = acc[f][r];
        __syncthreads();

        // scan: 4 threads/row, 16 cols each, running top-8 in registers
        const int sbase = srow * 65 + ssub * 16;
        #pragma unroll
        for (int i = 0; i < 16; ++i) {
            const int gc = c0 + ssub * 16 + i;
            const float v = simbuf[sbase + i];
            if (gc != growg && v > minv) {
                tv[minp] = v; ti[minp] = gc;
                minv = tv[0]; minp = 0;
                #pragma unroll
                for (int j = 1; j < 8; ++j)
                    if (tv[j] < minv) { minv = tv[j]; minp = j; }
            }
        }
        __syncthreads();   // simbuf free for next col-chunk
    }

    // merge the 4 sub-lists per row -> partial top-8 for this part
    float* mv = simbuf;                 // 2048 floats
    int*   mi = (int*)&simbuf[2048];    // 2048 ints
    #pragma unroll
    for (int j = 0; j < 8; ++j) {
        mv[(srow * 4 + ssub) * 8 + j] = tv[j];
        mi[(srow * 4 + ssub) * 8 + j] = ti[j];
    }
    __syncthreads();
    if (t < 64) {
        float fv[8]; int fi[8];
        #pragma unroll
        for (int j = 0; j < 8; ++j) { fv[j] = -2.0f; fi[j] = 0; }
        float fmin = -2.0f; int fmp = 0;
        for (int c = 0; c < 32; ++c) {
            const float v = mv[t * 32 + c];
            const int   g = mi[t * 32 + c];
            if (v > fmin) {
                fv[fmp] = v; fi[fmp] = g;
                fmin = fv[0]; fmp = 0;
                #pragma unroll
                for (int j = 1; j < 8; ++j)
                    if (fv[j] < fmin) { fmin = fv[j]; fmp = j; }
            }
        }
        const size_t base = ((size_t)(b * NPTS + r0 + t) * 4 + part) * 8;
        #pragma unroll
        for (int j = 0; j < 8; ++j) { ptv[base + j] = fv[j]; pti[base + j] = fi[j]; }
    }
}

// ---------------------------------------------------------------------------
// Merge 4 partial top-8 lists -> global top-8, softmax -> weights + indices.
// ---------------------------------------------------------------------------
__global__ __launch_bounds__(256)
void topk_merge(const float* __restrict__ ptv, const int* __restrict__ pti,
                float* __restrict__ tw, int* __restrict__ tidx) {
    const int row = blockIdx.x * 256 + threadIdx.x;
    float tv[8]; int ti[8];
    #pragma unroll
    for (int j = 0; j < 8; ++j) { tv[j] = -2.0f; ti[j] = 0; }
    float minv = -2.0f; int minp = 0;
    for (int c = 0; c < 32; ++c) {
        const float v = ptv[(size_t)row * 32 + c];
        const int   g = pti[(size_t)row * 32 + c];
        if (v > minv) {
            tv[minp] = v; ti[minp] = g;
            minv = tv[0]; minp = 0;
            #pragma unroll
            for (int j = 1; j < 8; ++j)
                if (tv[j] < minv) { minv = tv[j]; minp = j; }
        }
    }
    float m = tv[0];
    #pragma unroll
    for (int j = 1; j < 8; ++j) m = fmaxf(m, tv[j]);
    float e[8], Z = 0.0f;
    #pragma unroll
    for (int j = 0; j < 8; ++j) { e[j] = __expf(tv[j] - m); Z += e[j]; }
    const float inv = 1.0f / Z;
    #pragma unroll
    for (int j = 0; j < 8; ++j) {
        tw[(size_t)row * 8 + j]   = e[j] * inv;
        tidx[(size_t)row * 8 + j] = ti[j];
    }
}

// ---------------------------------------------------------------------------
// h <- LayerNorm(h[row] + sum_j w_j * V[idx_j])   (in-place over h)
// ---------------------------------------------------------------------------
__global__ __launch_bounds__(128)
void agg_ln(float* hio, const float* __restrict__ V,
            const int* __restrict__ tidx, const float* __restrict__ tw,
            const float* __restrict__ g, const float* __restrict__ be) {
    const int row = blockIdx.x;
    const int b   = row >> 12;
    const float* Vb = V + (size_t)b * NPTS * EMB;
    const int t = threadIdx.x;
    const int e = t * 4;
    float4 acc = *(const float4*)&hio[(size_t)row * EMB + e];
    #pragma unroll
    for (int j = 0; j < 8; ++j) {
        const int   idx = tidx[(size_t)row * 8 + j];
        const float w   = tw[(size_t)row * 8 + j];
        const float4 v  = *(const float4*)&Vb[(size_t)idx * EMB + e];
        acc.x = fmaf(w, v.x, acc.x);
        acc.y = fmaf(w, v.y, acc.y);
        acc.z = fmaf(w, v.z, acc.z);
        acc.w = fmaf(w, v.w, acc.w);
    }
    float s  = acc.x + acc.y + acc.z + acc.w;
    float ss = acc.x * acc.x + acc.y * acc.y + acc.z * acc.z + acc.w * acc.w;
    #pragma unroll
    for (int o = 32; o > 0; o >>= 1) { s += __shfl_xor(s, o); ss += __shfl_xor(ss, o); }
    __shared__ float red[4];
    if ((t & 63) == 0) { red[(t >> 6) * 2] = s; red[(t >> 6) * 2 + 1] = ss; }
    __syncthreads();
    s  = red[0] + red[2];
    ss = red[1] + red[3];
    const float mu   = s * (1.0f / EMB);
    const float var  = ss * (1.0f / EMB) - mu * mu;
    const float rstd = rsqrtf(var + 1e-5f);
    const float4 gg = *(const float4*)&g[e];
    const float4 bb = *(const float4*)&be[e];
    float4 o4;
    o4.x = (acc.x - mu) * rstd * gg.x + bb.x;
    o4.y = (acc.y - mu) * rstd * gg.y + bb.y;
    o4.z = (acc.z - mu) * rstd * gg.z + bb.z;
    o4.w = (acc.w - mu) * rstd * gg.w + bb.w;
    *(float4*)&hio[(size_t)row * EMB + e] = o4;
}

// ---------------------------------------------------------------------------
__global__ __launch_bounds__(256)
void score_kernel(const float* __restrict__ AV, const float* __restrict__ AU,
                  const float* __restrict__ aw_w, const float* __restrict__ aw_b,
                  float* __restrict__ score) {
    const int t    = threadIdx.x;
    const int row  = blockIdx.x * 4 + (t >> 6);
    const int lane = t & 63;
    float sum = 0.0f;
    #pragma unroll
    for (int i = 0; i < 2; ++i) {
        const int a = lane + i * 64;
        const float v = tanhf(AV[(size_t)row * ATT + a]);
        const float u = 1.0f / (1.0f + __expf(-AU[(size_t)row * ATT + a]));
        sum = fmaf(v * u, aw_w[a], sum);
    }
    #pragma unroll
    for (int o = 32; o > 0; o >>= 1) sum += __shfl_xor(sum, o);
    if (lane == 0) score[row] = sum + aw_b[0];
}

// ---------------------------------------------------------------------------
__global__ __launch_bounds__(256)
void softmax_kernel(const float* __restrict__ score, float* __restrict__ A,
                    float* __restrict__ bag) {
    const int b = blockIdx.x;
    const int t = threadIdx.x;
    const float* sb = score + b * NPTS;
    float loc[16];
    float m = -1e30f;
    #pragma unroll
    for (int i = 0; i < 16; ++i) { loc[i] = sb[t + i * 256]; m = fmaxf(m, loc[i]); }
    #pragma unroll
    for (int o = 32; o > 0; o >>= 1) m = fmaxf(m, __shfl_xor(m, o));
    __shared__ float redm[4];
    __shared__ float redz[4];
    if ((t & 63) == 0) redm[t >> 6] = m;
    __syncthreads();
    m = fmaxf(fmaxf(redm[0], redm[1]), fmaxf(redm[2], redm[3]));
    float Z = 0.0f;
    #pragma unroll
    for (int i = 0; i < 16; ++i) { loc[i] = __expf(loc[i] - m); Z += loc[i]; }
    #pragma unroll
    for (int o = 32; o > 0; o >>= 1) Z += __shfl_xor(Z, o);
    if ((t & 63) == 0) redz[t >> 6] = Z;
    __syncthreads();
    Z = redz[0] + redz[1] + redz[2] + redz[3];
    const float inv = 1.0f / Z;
    #pragma unroll
    for (int i = 0; i < 16; ++i) A[b * NPTS + t + i * 256] = loc[i] * inv;
    bag[b * EMB + t]       = 0.0f;
    bag[b * EMB + t + 256] = 0.0f;
}

// ---------------------------------------------------------------------------
__global__ __launch_bounds__(512)
void bagpart_kernel(const float* __restrict__ A, const float* __restrict__ h2,
                    float* __restrict__ bag) {
    const int b = blockIdx.y;
    const int s = blockIdx.x;
    const int e = threadIdx.x;
    const int n0 = s * 256;
    float acc = 0.0f;
    for (int n = 0; n < 256; ++n) {
        const float a = A[b * NPTS + n0 + n];
        acc = fmaf(a, h2[(size_t)(b * NPTS + n0 + n) * EMB + e], acc);
    }
    atomicAdd(&bag[b * EMB + e], acc);
}

// ---------------------------------------------------------------------------
__global__ __launch_bounds__(512)
void logits_kernel(const float* __restrict__ bag, const float* __restrict__ cls_w,
                   const float* __restrict__ cls_b, float* __restrict__ out) {
    const int t    = threadIdx.x;
    const int w    = t >> 6;
    const int lane = t & 63;
    const int b = w >> 1, c = w & 1;
    float sum = 0.0f;
    #pragma unroll
    for (int i = 0; i < 8; ++i) {
        const int e = lane + i * 64;
        sum = fmaf(bag[b * EMB + e], cls_w[e * NCLS + c], sum);
    }
    #pragma unroll
    for (int o = 32; o > 0; o >>= 1) sum += __shfl_xor(sum, o);
    if (lane == 0) out[b * NCLS + c] = sum + cls_b[c];
}

// ---------------------------------------------------------------------------
extern "C" void kernel_launch(void* const* d_in, const int* in_sizes, int n_in,
                              void* d_out, int out_size, void* d_ws, size_t ws_size,
                              hipStream_t stream) {
    const float* x     = (const float*)d_in[0];
    const float* pe_w  = (const float*)d_in[1];
    const float* pe_b  = (const float*)d_in[2];
    const float* wv_w  = (const float*)d_in[3];
    const float* wv_b  = (const float*)d_in[4];
    const float* ln_g  = (const float*)d_in[5];
    const float* ln_b  = (const float*)d_in[6];
    const float* av_w  = (const float*)d_in[7];
    const float* av_b  = (const float*)d_in[8];
    const float* au_w  = (const float*)d_in[9];
    const float* au_b  = (const float*)d_in[10];
    const float* aw_w  = (const float*)d_in[11];
    const float* aw_b  = (const float*)d_in[12];
    const float* cls_w = (const float*)d_in[13];
    const float* cls_b = (const float*)d_in[14];

    char* ws = (char*)d_ws;
    // h [0, 33.5M).  Region [33.5M, 67.1M): hn (bf16, dead after simtopk)
    // then V (fp32, written after merge), then AV/AU.  Tail: topk scratch.
    float*  h     = (float*)(ws + 0);
    ushort* hn    = (ushort*)(ws + 33554432);
    float*  V     = (float*)(ws + 33554432);
    float*  AV    = V;
    float*  AU    = (float*)(ws + 33554432 + 16777216);
    int*    tidx  = (int*)  (ws + 67108864);
    float*  tw    = (float*)(ws + 67633152);
    float*  scoreb= (float*)(ws + 68157440);
    float*  Asm   = (float*)(ws + 68222976);
    float*  bag   = (float*)(ws + 68288512);
    float*  ptv   = (float*)(ws + 68354048);
    int*    pti   = (int*)  (ws + 70451200);

    const int M = BATCH * NPTS;  // 16384

    // 1) h = x @ pe_w + pe_b
    gemm_bias<INDIM><<<dim3(EMB / 64, M / 64), dim3(256), 0, stream>>>(x, pe_w, pe_b, h, EMB);
    // 2) hn = bf16(normalize(h))
    normcast_kernel<<<dim3(M), dim3(64), 0, stream>>>(h, hn);
    // 3) MFMA cosine-sim + partial top-8
    simtopk_mfma<<<dim3(NPTS / 64, 4, BATCH), dim3(256), 0, stream>>>(hn, ptv, pti);
    // 4) merge partials -> softmaxed weights + indices
    topk_merge<<<dim3(M / 256), dim3(256), 0, stream>>>(ptv, pti, tw, tidx);
    // 5) V = h @ wv_w + wv_b   (hn dead now; V overlays it)
    gemm_bias<EMB><<<dim3(EMB / 64, M / 64), dim3(256), 0, stream>>>(h, wv_w, wv_b, V, EMB);
    // 6) h <- LN(h + gather(V))
    agg_ln<<<dim3(M), dim3(128), 0, stream>>>(h, V, tidx, tw, ln_g, ln_b);
    // 7) AV/AU pre-activations
    gemm_bias<EMB><<<dim3(ATT / 64, M / 64), dim3(256), 0, stream>>>(h, av_w, av_b, AV, ATT);
    gemm_bias<EMB><<<dim3(ATT / 64, M / 64), dim3(256), 0, stream>>>(h, au_w, au_b, AU, ATT);
    // 8) gated-attention scores
    score_kernel<<<dim3(M / 4), dim3(256), 0, stream>>>(AV, AU, aw_w, aw_b, scoreb);
    // 9) per-batch softmax (+ zero bag)
    softmax_kernel<<<dim3(BATCH), dim3(256), 0, stream>>>(scoreb, Asm, bag);
    // 10) weighted pooling
    bagpart_kernel<<<dim3(16, BATCH), dim3(512), 0, stream>>>(Asm, h, bag);
    // 11) classifier
    logits_kernel<<<dim3(1), dim3(512), 0, stream>>>(bag, cls_w, cls_b, (float*)d_out);
}

// Round 5
// 1126.121 us; speedup vs baseline: 1.6659x; 1.0097x over previous
//
#include <hip/hip_runtime.h>

#define BATCH 4
#define NPTS  4096
#define INDIM 1024
#define EMB   512
#define ATT   128
#define KNN   8
#define NCLS  2

typedef __attribute__((ext_vector_type(8))) short bf16x8;
typedef __attribute__((ext_vector_type(4))) float f32x4;

// ---------------------------------------------------------------------------
// Tiled fp32 GEMM:  C[M,Nc] = A[M,K] @ W[K,Nc] + bias[Nc]
// ---------------------------------------------------------------------------
template<int K>
__global__ __launch_bounds__(256)
void gemm_bias(const float* __restrict__ A, const float* __restrict__ W,
               const float* __restrict__ bias, float* __restrict__ C, int Nc) {
    __shared__ float As[16][68];
    __shared__ float Ws[16][68];
    const int r0 = blockIdx.y * 64;
    const int c0 = blockIdx.x * 64;
    const int t  = threadIdx.x;
    const int tx = t & 15, ty = t >> 4;
    const int lrow = t >> 2, lkc = (t & 3) * 4;
    const int wkk  = t >> 4, wcc = (t & 15) * 4;
    float acc[4][4] = {};
    for (int k0 = 0; k0 < K; k0 += 16) {
        const float4 a4 = *(const float4*)&A[(size_t)(r0 + lrow) * K + k0 + lkc];
        As[lkc + 0][lrow] = a4.x;
        As[lkc + 1][lrow] = a4.y;
        As[lkc + 2][lrow] = a4.z;
        As[lkc + 3][lrow] = a4.w;
        *(float4*)&Ws[wkk][wcc] = *(const float4*)&W[(size_t)(k0 + wkk) * Nc + c0 + wcc];
        __syncthreads();
        #pragma unroll
        for (int k = 0; k < 16; ++k) {
            const float4 a = *(const float4*)&As[k][ty * 4];
            const float4 b = *(const float4*)&Ws[k][tx * 4];
            const float a_[4] = {a.x, a.y, a.z, a.w};
            const float b_[4] = {b.x, b.y, b.z, b.w};
            #pragma unroll
            for (int i = 0; i < 4; ++i)
                #pragma unroll
                for (int j = 0; j < 4; ++j)
                    acc[i][j] = fmaf(a_[i], b_[j], acc[i][j]);
        }
        __syncthreads();
    }
    const float4 b4 = *(const float4*)&bias[c0 + tx * 4];
    #pragma unroll
    for (int i = 0; i < 4; ++i) {
        float4 o;
        o.x = acc[i][0] + b4.x;
        o.y = acc[i][1] + b4.y;
        o.z = acc[i][2] + b4.z;
        o.w = acc[i][3] + b4.w;
        *(float4*)&C[(size_t)(r0 + ty * 4 + i) * Nc + c0 + tx * 4] = o;
    }
}

// ---------------------------------------------------------------------------
// Normalize rows of h (fp32) -> hn (bf16).  One 64-thread block per row.
// ---------------------------------------------------------------------------
__device__ __forceinline__ ushort f2bf(float x) {
    unsigned u = __float_as_uint(x);
    u += 0x7fff + ((u >> 16) & 1);   // RNE
    return (ushort)(u >> 16);
}

__global__ __launch_bounds__(64)
void normcast_kernel(const float* __restrict__ h, ushort* __restrict__ hn) {
    const int row  = blockIdx.x;
    const int lane = threadIdx.x;
    const float4 v0 = *(const float4*)&h[(size_t)row * EMB + lane * 8];
    const float4 v1 = *(const float4*)&h[(size_t)row * EMB + lane * 8 + 4];
    float ss = v0.x * v0.x + v0.y * v0.y + v0.z * v0.z + v0.w * v0.w
             + v1.x * v1.x + v1.y * v1.y + v1.z * v1.z + v1.w * v1.w;
    #pragma unroll
    for (int o = 32; o > 0; o >>= 1) ss += __shfl_xor(ss, o);
    const float rn = 1.0f / fmaxf(sqrtf(ss), 1e-12f);
    uint4 o4;
    o4.x = (unsigned)f2bf(v0.x * rn) | ((unsigned)f2bf(v0.y * rn) << 16);
    o4.y = (unsigned)f2bf(v0.z * rn) | ((unsigned)f2bf(v0.w * rn) << 16);
    o4.z = (unsigned)f2bf(v1.x * rn) | ((unsigned)f2bf(v1.y * rn) << 16);
    o4.w = (unsigned)f2bf(v1.z * rn) | ((unsigned)f2bf(v1.w * rn) << 16);
    *(uint4*)&hn[(size_t)row * EMB + lane * 8] = o4;
}

// ---------------------------------------------------------------------------
// MFMA cosine-sim + running top-8, v2.
//  - 1D grid 1024, bijective XCD swizzle (8 x 128).
//  - Block: 256 thr (4 waves) = 64 rows; part = 1024 cols = 8 chunks x 128.
//  - A fragments (16 rows x K=512 per wave) held in registers, loaded once.
//  - B: 128-col x 64-k tiles, double-buffered, XOR-swizzled LDS.
//  - 16 MFMAs per barrier region; scan in two 64-col halves.
// ---------------------------------------------------------------------------
__global__ __launch_bounds__(256, 3)
void simtopk_mfma(const ushort* __restrict__ hn,
                  float* __restrict__ ptv, int* __restrict__ pti) {
    const int orig = blockIdx.x;
    const int wg   = (orig & 7) * 128 + (orig >> 3);   // bijective XCD swizzle
    const int b    = wg >> 8;          // batch
    const int part = (wg >> 6) & 3;    // 4 parts x 1024 cols
    const int rb   = wg & 63;          // 64 row-blocks
    const int r0   = rb * 64;
    const ushort* hb = hn + (size_t)b * NPTS * EMB;

    __shared__ ushort Bs[2][8192];     // [buf][128 cols][64 k] bf16, swizzled (16 KB ea)
    __shared__ float  simbuf[64 * 65]; // pitch-65 scan buffer (16.6 KB)

    const int t    = threadIdx.x;
    const int wave = t >> 6;
    const int lane = t & 63;

    // ---- A fragments in registers: wave's 16 rows, full K=512 ----
    const int arow  = r0 + wave * 16 + (lane & 15);
    const int akoff = (lane >> 4) * 8;
    bf16x8 a_reg[16];
    #pragma unroll
    for (int kk = 0; kk < 16; ++kk)
        a_reg[kk] = *(const bf16x8*)&hb[(size_t)arow * EMB + kk * 32 + akoff];

    // ---- B staging map: 1024 16B-pieces; thread t -> pieces t,+256,+512,+768
    const int sc  = t >> 3;            // base col 0..31
    const int skb = (t & 7) * 16;      // byte offset in 128B k-row
    int scol[4], sdst[4];
    #pragma unroll
    for (int i = 0; i < 4; ++i) {
        scol[i] = sc + i * 32;
        sdst[i] = scol[i] * 64 + ((skb ^ ((scol[i] & 7) << 4)) >> 1);  // ushort idx
    }

    // scan mapping: 4 threads per row, 16 cols each
    const int srow = t >> 2, ssub = t & 3;
    const int growg = r0 + srow;

    float tv[8]; int ti[8];
    #pragma unroll
    for (int j = 0; j < 8; ++j) { tv[j] = -2.0f; ti[j] = 0; }
    float minv = -2.0f; int minp = 0;

    uint4 rg[4];
    const int cpart = part * 1024;

    #define GLOADC(cbase, k0)                                                      \
        { _Pragma("unroll")                                                        \
          for (int i = 0; i < 4; ++i)                                              \
              rg[i] = *(const uint4*)&hb[(size_t)((cbase) + scol[i]) * EMB + (k0) + (skb >> 1)]; }
    #define SWRITEB(buf)                                                           \
        { _Pragma("unroll")                                                        \
          for (int i = 0; i < 4; ++i)                                              \
              *(uint4*)&Bs[buf][sdst[i]] = rg[i]; }

    GLOADC(cpart, 0)                       // chunk 0, k0=0

    for (int cc = 0; cc < 8; ++cc) {
        const int c0 = cpart + cc * 128;

        f32x4 acc[8];
        #pragma unroll
        for (int f = 0; f < 8; ++f) acc[f] = (f32x4){0.f, 0.f, 0.f, 0.f};

        SWRITEB(0)                         // data (cc, k0=0)
        GLOADC(c0, 64)                     // k0=64

        #pragma unroll
        for (int kc = 0; kc < 8; ++kc) {
            __syncthreads();               // buf[kc&1] ready for all waves
            if (kc < 7) { SWRITEB((kc + 1) & 1) }
            if (kc < 6)      { GLOADC(c0, (kc + 2) * 64) }
            else if (kc == 6){ GLOADC(cpart + ((cc + 1) & 7) * 128, 0) }  // next chunk
            #pragma unroll
            for (int ks = 0; ks < 2; ++ks) {
                const int kb = ks * 64 + (lane >> 4) * 16;
                #pragma unroll
                for (int f = 0; f < 8; ++f) {
                    const int bcol = f * 16 + (lane & 15);
                    const bf16x8 bb = *(const bf16x8*)
                        ((const char*)&Bs[kc & 1][0] + bcol * 128 + (kb ^ ((bcol & 7) << 4)));
                    acc[f] = __builtin_amdgcn_mfma_f32_16x16x32_bf16(
                        a_reg[kc * 2 + ks], bb, acc[f], 0, 0, 0);
                }
            }
        }

        // scan the 128 cols in two 64-col halves
        #pragma unroll
        for (int h = 0; h < 2; ++h) {
            __syncthreads();               // previous simbuf readers done
            #pragma unroll
            for (int f = 0; f < 4; ++f)
                #pragma unroll
                for (int r = 0; r < 4; ++r)
                    simbuf[(wave * 16 + (lane >> 4) * 4 + r) * 65 + f * 16 + (lane & 15)]
                        = acc[h * 4 + f][r];
            __syncthreads();
            const int sbase = srow * 65 + ssub * 16;
            const int cbase = c0 + h * 64 + ssub * 16;
            #pragma unroll
            for (int i = 0; i < 16; ++i) {
                const int gc = cbase + i;
                const float v = simbuf[sbase + i];
                if (gc != growg && v > minv) {
                    tv[minp] = v; ti[minp] = gc;
                    minv = tv[0]; minp = 0;
                    #pragma unroll
                    for (int j = 1; j < 8; ++j)
                        if (tv[j] < minv) { minv = tv[j]; minp = j; }
                }
            }
        }
    }
    #undef GLOADC
    #undef SWRITEB

    // merge the 4 sub-lists per row -> partial top-8 for this part
    __syncthreads();
    float* mv = simbuf;                 // 2048 floats
    int*   mi = (int*)&simbuf[2048];    // 2048 ints
    #pragma unroll
    for (int j = 0; j < 8; ++j) {
        mv[(srow * 4 + ssub) * 8 + j] = tv[j];
        mi[(srow * 4 + ssub) * 8 + j] = ti[j];
    }
    __syncthreads();
    if (t < 64) {
        float fv[8]; int fi[8];
        #pragma unroll
        for (int j = 0; j < 8; ++j) { fv[j] = -2.0f; fi[j] = 0; }
        float fmin = -2.0f; int fmp = 0;
        for (int c = 0; c < 32; ++c) {
            const float v = mv[t * 32 + c];
            const int   g = mi[t * 32 + c];
            if (v > fmin) {
                fv[fmp] = v; fi[fmp] = g;
                fmin = fv[0]; fmp = 0;
                #pragma unroll
                for (int j = 1; j < 8; ++j)
                    if (fv[j] < fmin) { fmin = fv[j]; fmp = j; }
            }
        }
        const size_t base = ((size_t)(b * NPTS + r0 + t) * 4 + part) * 8;
        #pragma unroll
        for (int j = 0; j < 8; ++j) { ptv[base + j] = fv[j]; pti[base + j] = fi[j]; }
    }
}

// ---------------------------------------------------------------------------
// Merge 4 partial top-8 lists -> global top-8, softmax -> weights + indices.
// ---------------------------------------------------------------------------
__global__ __launch_bounds__(256)
void topk_merge(const float* __restrict__ ptv, const int* __restrict__ pti,
                float* __restrict__ tw, int* __restrict__ tidx) {
    const int row = blockIdx.x * 256 + threadIdx.x;
    float tv[8]; int ti[8];
    #pragma unroll
    for (int j = 0; j < 8; ++j) { tv[j] = -2.0f; ti[j] = 0; }
    float minv = -2.0f; int minp = 0;
    for (int c = 0; c < 32; ++c) {
        const float v = ptv[(size_t)row * 32 + c];
        const int   g = pti[(size_t)row * 32 + c];
        if (v > minv) {
            tv[minp] = v; ti[minp] = g;
            minv = tv[0]; minp = 0;
            #pragma unroll
            for (int j = 1; j < 8; ++j)
                if (tv[j] < minv) { minv = tv[j]; minp = j; }
        }
    }
    float m = tv[0];
    #pragma unroll
    for (int j = 1; j < 8; ++j) m = fmaxf(m, tv[j]);
    float e[8], Z = 0.0f;
    #pragma unroll
    for (int j = 0; j < 8; ++j) { e[j] = __expf(tv[j] - m); Z += e[j]; }
    const float inv = 1.0f / Z;
    #pragma unroll
    for (int j = 0; j < 8; ++j) {
        tw[(size_t)row * 8 + j]   = e[j] * inv;
        tidx[(size_t)row * 8 + j] = ti[j];
    }
}

// ---------------------------------------------------------------------------
// h <- LayerNorm(h[row] + sum_j w_j * V[idx_j])   (in-place over h)
// ---------------------------------------------------------------------------
__global__ __launch_bounds__(128)
void agg_ln(float* hio, const float* __restrict__ V,
            const int* __restrict__ tidx, const float* __restrict__ tw,
            const float* __restrict__ g, const float* __restrict__ be) {
    const int row = blockIdx.x;
    const int b   = row >> 12;
    const float* Vb = V + (size_t)b * NPTS * EMB;
    const int t = threadIdx.x;
    const int e = t * 4;
    float4 acc = *(const float4*)&hio[(size_t)row * EMB + e];
    #pragma unroll
    for (int j = 0; j < 8; ++j) {
        const int   idx = tidx[(size_t)row * 8 + j];
        const float w   = tw[(size_t)row * 8 + j];
        const float4 v  = *(const float4*)&Vb[(size_t)idx * EMB + e];
        acc.x = fmaf(w, v.x, acc.x);
        acc.y = fmaf(w, v.y, acc.y);
        acc.z = fmaf(w, v.z, acc.z);
        acc.w = fmaf(w, v.w, acc.w);
    }
    float s  = acc.x + acc.y + acc.z + acc.w;
    float ss = acc.x * acc.x + acc.y * acc.y + acc.z * acc.z + acc.w * acc.w;
    #pragma unroll
    for (int o = 32; o > 0; o >>= 1) { s += __shfl_xor(s, o); ss += __shfl_xor(ss, o); }
    __shared__ float red[4];
    if ((t & 63) == 0) { red[(t >> 6) * 2] = s; red[(t >> 6) * 2 + 1] = ss; }
    __syncthreads();
    s  = red[0] + red[2];
    ss = red[1] + red[3];
    const float mu   = s * (1.0f / EMB);
    const float var  = ss * (1.0f / EMB) - mu * mu;
    const float rstd = rsqrtf(var + 1e-5f);
    const float4 gg = *(const float4*)&g[e];
    const float4 bb = *(const float4*)&be[e];
    float4 o4;
    o4.x = (acc.x - mu) * rstd * gg.x + bb.x;
    o4.y = (acc.y - mu) * rstd * gg.y + bb.y;
    o4.z = (acc.z - mu) * rstd * gg.z + bb.z;
    o4.w = (acc.w - mu) * rstd * gg.w + bb.w;
    *(float4*)&hio[(size_t)row * EMB + e] = o4;
}

// ---------------------------------------------------------------------------
__global__ __launch_bounds__(256)
void score_kernel(const float* __restrict__ AV, const float* __restrict__ AU,
                  const float* __restrict__ aw_w, const float* __restrict__ aw_b,
                  float* __restrict__ score) {
    const int t    = threadIdx.x;
    const int row  = blockIdx.x * 4 + (t >> 6);
    const int lane = t & 63;
    float sum = 0.0f;
    #pragma unroll
    for (int i = 0; i < 2; ++i) {
        const int a = lane + i * 64;
        const float v = tanhf(AV[(size_t)row * ATT + a]);
        const float u = 1.0f / (1.0f + __expf(-AU[(size_t)row * ATT + a]));
        sum = fmaf(v * u, aw_w[a], sum);
    }
    #pragma unroll
    for (int o = 32; o > 0; o >>= 1) sum += __shfl_xor(sum, o);
    if (lane == 0) score[row] = sum + aw_b[0];
}

// ---------------------------------------------------------------------------
__global__ __launch_bounds__(256)
void softmax_kernel(const float* __restrict__ score, float* __restrict__ A,
                    float* __restrict__ bag) {
    const int b = blockIdx.x;
    const int t = threadIdx.x;
    const float* sb = score + b * NPTS;
    float loc[16];
    float m = -1e30f;
    #pragma unroll
    for (int i = 0; i < 16; ++i) { loc[i] = sb[t + i * 256]; m = fmaxf(m, loc[i]); }
    #pragma unroll
    for (int o = 32; o > 0; o >>= 1) m = fmaxf(m, __shfl_xor(m, o));
    __shared__ float redm[4];
    __shared__ float redz[4];
    if ((t & 63) == 0) redm[t >> 6] = m;
    __syncthreads();
    m = fmaxf(fmaxf(redm[0], redm[1]), fmaxf(redm[2], redm[3]));
    float Z = 0.0f;
    #pragma unroll
    for (int i = 0; i < 16; ++i) { loc[i] = __expf(loc[i] - m); Z += loc[i]; }
    #pragma unroll
    for (int o = 32; o > 0; o >>= 1) Z += __shfl_xor(Z, o);
    if ((t & 63) == 0) redz[t >> 6] = Z;
    __syncthreads();
    Z = redz[0] + redz[1] + redz[2] + redz[3];
    const float inv = 1.0f / Z;
    #pragma unroll
    for (int i = 0; i < 16; ++i) A[b * NPTS + t + i * 256] = loc[i] * inv;
    bag[b * EMB + t]       = 0.0f;
    bag[b * EMB + t + 256] = 0.0f;
}

// ---------------------------------------------------------------------------
__global__ __launch_bounds__(512)
void bagpart_kernel(const float* __restrict__ A, const float* __restrict__ h2,
                    float* __restrict__ bag) {
    const int b = blockIdx.y;
    const int s = blockIdx.x;
    const int e = threadIdx.x;
    const int n0 = s * 256;
    float acc = 0.0f;
    for (int n = 0; n < 256; ++n) {
        const float a = A[b * NPTS + n0 + n];
        acc = fmaf(a, h2[(size_t)(b * NPTS + n0 + n) * EMB + e], acc);
    }
    atomicAdd(&bag[b * EMB + e], acc);
}

// ---------------------------------------------------------------------------
__global__ __launch_bounds__(512)
void logits_kernel(const float* __restrict__ bag, const float* __restrict__ cls_w,
                   const float* __restrict__ cls_b, float* __restrict__ out) {
    const int t    = threadIdx.x;
    const int w    = t >> 6;
    const int lane = t & 63;
    const int b = w >> 1, c = w & 1;
    float sum = 0.0f;
    #pragma unroll
    for (int i = 0; i < 8; ++i) {
        const int e = lane + i * 64;
        sum = fmaf(bag[b * EMB + e], cls_w[e * NCLS + c], sum);
    }
    #pragma unroll
    for (int o = 32; o > 0; o >>= 1) sum += __shfl_xor(sum, o);
    if (lane == 0) out[b * NCLS + c] = sum + cls_b[c];
}

// ---------------------------------------------------------------------------
extern "C" void kernel_launch(void* const* d_in, const int* in_sizes, int n_in,
                              void* d_out, int out_size, void* d_ws, size_t ws_size,
                              hipStream_t stream) {
    const float* x     = (const float*)d_in[0];
    const float* pe_w  = (const float*)d_in[1];
    const float* pe_b  = (const float*)d_in[2];
    const float* wv_w  = (const float*)d_in[3];
    const float* wv_b  = (const float*)d_in[4];
    const float* ln_g  = (const float*)d_in[5];
    const float* ln_b  = (const float*)d_in[6];
    const float* av_w  = (const float*)d_in[7];
    const float* av_b  = (const float*)d_in[8];
    const float* au_w  = (const float*)d_in[9];
    const float* au_b  = (const float*)d_in[10];
    const float* aw_w  = (const float*)d_in[11];
    const float* aw_b  = (const float*)d_in[12];
    const float* cls_w = (const float*)d_in[13];
    const float* cls_b = (const float*)d_in[14];

    char* ws = (char*)d_ws;
    float*  h     = (float*)(ws + 0);
    ushort* hn    = (ushort*)(ws + 33554432);
    float*  V     = (float*)(ws + 33554432);
    float*  AV    = V;
    float*  AU    = (float*)(ws + 33554432 + 16777216);
    int*    tidx  = (int*)  (ws + 67108864);
    float*  tw    = (float*)(ws + 67633152);
    float*  scoreb= (float*)(ws + 68157440);
    float*  Asm   = (float*)(ws + 68222976);
    float*  bag   = (float*)(ws + 68288512);
    float*  ptv   = (float*)(ws + 68354048);
    int*    pti   = (int*)  (ws + 70451200);

    const int M = BATCH * NPTS;  // 16384

    // 1) h = x @ pe_w + pe_b
    gemm_bias<INDIM><<<dim3(EMB / 64, M / 64), dim3(256), 0, stream>>>(x, pe_w, pe_b, h, EMB);
    // 2) hn = bf16(normalize(h))
    normcast_kernel<<<dim3(M), dim3(64), 0, stream>>>(h, hn);
    // 3) MFMA cosine-sim + partial top-8  (1D grid, XCD-swizzled)
    simtopk_mfma<<<dim3(1024), dim3(256), 0, stream>>>(hn, ptv, pti);
    // 4) merge partials -> softmaxed weights + indices
    topk_merge<<<dim3(M / 256), dim3(256), 0, stream>>>(ptv, pti, tw, tidx);
    // 5) V = h @ wv_w + wv_b   (hn dead now; V overlays it)
    gemm_bias<EMB><<<dim3(EMB / 64, M / 64), dim3(256), 0, stream>>>(h, wv_w, wv_b, V, EMB);
    // 6) h <- LN(h + gather(V))
    agg_ln<<<dim3(M), dim3(128), 0, stream>>>(h, V, tidx, tw, ln_g, ln_b);
    // 7) AV/AU pre-activations
    gemm_bias<EMB><<<dim3(ATT / 64, M / 64), dim3(256), 0, stream>>>(h, av_w, av_b, AV, ATT);
    gemm_bias<EMB><<<dim3(ATT / 64, M / 64), dim3(256), 0, stream>>>(h, au_w, au_b, AU, ATT);
    // 8) gated-attention scores
    score_kernel<<<dim3(M / 4), dim3(256), 0, stream>>>(AV, AU, aw_w, aw_b, scoreb);
    // 9) per-batch softmax (+ zero bag)
    softmax_kernel<<<dim3(BATCH), dim3(256), 0, stream>>>(scoreb, Asm, bag);
    // 10) weighted pooling
    bagpart_kernel<<<dim3(16, BATCH), dim3(512), 0, stream>>>(Asm, h, bag);
    // 11) classifier
    logits_kernel<<<dim3(1), dim3(512), 0, stream>>>(bag, cls_w, cls_b, (float*)d_out);
}

// Round 10
// 877.942 us; speedup vs baseline: 2.1369x; 1.2827x over previous
//
#include <hip/hip_runtime.h>

#define BATCH 4
#define NPTS  4096
#define INDIM 1024
#define EMB   512
#define ATT   128
#define KNN   8
#define NCLS  2

typedef __attribute__((ext_vector_type(8))) short bf16x8;
typedef __attribute__((ext_vector_type(4))) float f32x4;

// ---------------------------------------------------------------------------
// Tiled fp32 GEMM:  C[M,Nc] = A[M,K] @ W[K,Nc] + bias[Nc]
// ---------------------------------------------------------------------------
template<int K>
__global__ __launch_bounds__(256)
void gemm_bias(const float* __restrict__ A, const float* __restrict__ W,
               const float* __restrict__ bias, float* __restrict__ C, int Nc) {
    __shared__ float As[16][68];
    __shared__ float Ws[16][68];
    const int r0 = blockIdx.y * 64;
    const int c0 = blockIdx.x * 64;
    const int t  = threadIdx.x;
    const int tx = t & 15, ty = t >> 4;
    const int lrow = t >> 2, lkc = (t & 3) * 4;
    const int wkk  = t >> 4, wcc = (t & 15) * 4;
    float acc[4][4] = {};
    for (int k0 = 0; k0 < K; k0 += 16) {
        const float4 a4 = *(const float4*)&A[(size_t)(r0 + lrow) * K + k0 + lkc];
        As[lkc + 0][lrow] = a4.x;
        As[lkc + 1][lrow] = a4.y;
        As[lkc + 2][lrow] = a4.z;
        As[lkc + 3][lrow] = a4.w;
        *(float4*)&Ws[wkk][wcc] = *(const float4*)&W[(size_t)(k0 + wkk) * Nc + c0 + wcc];
        __syncthreads();
        #pragma unroll
        for (int k = 0; k < 16; ++k) {
            const float4 a = *(const float4*)&As[k][ty * 4];
            const float4 b = *(const float4*)&Ws[k][tx * 4];
            const float a_[4] = {a.x, a.y, a.z, a.w};
            const float b_[4] = {b.x, b.y, b.z, b.w};
            #pragma unroll
            for (int i = 0; i < 4; ++i)
                #pragma unroll
                for (int j = 0; j < 4; ++j)
                    acc[i][j] = fmaf(a_[i], b_[j], acc[i][j]);
        }
        __syncthreads();
    }
    const float4 b4 = *(const float4*)&bias[c0 + tx * 4];
    #pragma unroll
    for (int i = 0; i < 4; ++i) {
        float4 o;
        o.x = acc[i][0] + b4.x;
        o.y = acc[i][1] + b4.y;
        o.z = acc[i][2] + b4.z;
        o.w = acc[i][3] + b4.w;
        *(float4*)&C[(size_t)(r0 + ty * 4 + i) * Nc + c0 + tx * 4] = o;
    }
}

// ---------------------------------------------------------------------------
// Normalize rows of h (fp32) -> hn (bf16).  One 64-thread block per row.
// ---------------------------------------------------------------------------
__device__ __forceinline__ ushort f2bf(float x) {
    unsigned u = __float_as_uint(x);
    u += 0x7fff + ((u >> 16) & 1);   // RNE
    return (ushort)(u >> 16);
}

__global__ __launch_bounds__(64)
void normcast_kernel(const float* __restrict__ h, ushort* __restrict__ hn) {
    const int row  = blockIdx.x;
    const int lane = threadIdx.x;
    const float4 v0 = *(const float4*)&h[(size_t)row * EMB + lane * 8];
    const float4 v1 = *(const float4*)&h[(size_t)row * EMB + lane * 8 + 4];
    float ss = v0.x * v0.x + v0.y * v0.y + v0.z * v0.z + v0.w * v0.w
             + v1.x * v1.x + v1.y * v1.y + v1.z * v1.z + v1.w * v1.w;
    #pragma unroll
    for (int o = 32; o > 0; o >>= 1) ss += __shfl_xor(ss, o);
    const float rn = 1.0f / fmaxf(sqrtf(ss), 1e-12f);
    uint4 o4;
    o4.x = (unsigned)f2bf(v0.x * rn) | ((unsigned)f2bf(v0.y * rn) << 16);
    o4.y = (unsigned)f2bf(v0.z * rn) | ((unsigned)f2bf(v0.w * rn) << 16);
    o4.z = (unsigned)f2bf(v1.x * rn) | ((unsigned)f2bf(v1.y * rn) << 16);
    o4.w = (unsigned)f2bf(v1.z * rn) | ((unsigned)f2bf(v1.w * rn) << 16);
    *(uint4*)&hn[(size_t)row * EMB + lane * 8] = o4;
}

// ---------------------------------------------------------------------------
// MFMA cosine-sim + running top-8, v3: barrier-free, LDS-free main loop.
//  - Swapped operands: mfma(col_frag, row_frag) -> each lane's acc holds
//    4 candidate cols for ITS OWN row (row = lane&15 of the wave's 32 rows).
//  - A (32 rows x K=512 per wave) in registers, loaded once from global.
//  - B col-fragments (16 cols x K=512) loaded straight from global (L2-hot).
//  - Per-lane running top-8 in registers; tiny padded-LDS merge at the end.
//  - 512 blocks, bijective XCD swizzle (8 x 64): per-XCD B set = 2 MB (L2).
// ---------------------------------------------------------------------------
__global__ __launch_bounds__(256, 2)
void simtopk_mfma(const ushort* __restrict__ hn,
                  float* __restrict__ ptv, int* __restrict__ pti) {
    const int orig = blockIdx.x;
    const int wg   = (orig & 7) * 64 + (orig >> 3);   // bijective: 512 = 8*64
    const int b    = wg >> 7;          // batch (128 blocks each)
    const int part = (wg >> 5) & 3;    // 4 parts x 1024 cols
    const int rb   = wg & 31;          // 32 row-blocks x 128 rows
    const ushort* hb = hn + (size_t)b * NPTS * EMB;

    const int t    = threadIdx.x;
    const int wave = t >> 6;
    const int lane = t & 63;
    const int lrow = lane & 15;        // operand dim index
    const int lkg  = lane >> 4;        // k-group

    const int rowbase = rb * 128 + wave * 32;

    // ---- A fragments (as MFMA B-operand): 2 rowsets x 16 rows, full K ----
    bf16x8 a_reg[2][16];
    #pragma unroll
    for (int rs = 0; rs < 2; ++rs) {
        const size_t abase = (size_t)(rowbase + rs * 16 + lrow) * EMB + lkg * 8;
        #pragma unroll
        for (int kk = 0; kk < 16; ++kk)
            a_reg[rs][kk] = *(const bf16x8*)&hb[abase + kk * 32];
    }

    float tv[2][8]; int ti[2][8];
    float minv[2]; int minp[2];
    #pragma unroll
    for (int rs = 0; rs < 2; ++rs) {
        minv[rs] = -2.0f; minp[rs] = 0;
        #pragma unroll
        for (int j = 0; j < 8; ++j) { tv[rs][j] = -2.0f; ti[rs][j] = 0; }
    }

    const int row0 = rowbase + lrow;
    const int row1 = rowbase + 16 + lrow;
    const int cpart = part * 1024;

    for (int cf = 0; cf < 64; ++cf) {
        const int c0 = cpart + cf * 16;
        // col-fragment (as MFMA A-operand): 16 cols x full K
        bf16x8 bf[16];
        const size_t bbase = (size_t)(c0 + lrow) * EMB + lkg * 8;
        #pragma unroll
        for (int kk = 0; kk < 16; ++kk)
            bf[kk] = *(const bf16x8*)&hb[bbase + kk * 32];

        f32x4 acc0 = {0.f, 0.f, 0.f, 0.f};
        f32x4 acc1 = {0.f, 0.f, 0.f, 0.f};
        #pragma unroll
        for (int kk = 0; kk < 16; ++kk) {
            acc0 = __builtin_amdgcn_mfma_f32_16x16x32_bf16(bf[kk], a_reg[0][kk], acc0, 0, 0, 0);
            acc1 = __builtin_amdgcn_mfma_f32_16x16x32_bf16(bf[kk], a_reg[1][kk], acc1, 0, 0, 0);
        }

        // scan: lane's cols are c0 + lkg*4 + r, for its rows row0/row1
        #pragma unroll
        for (int r = 0; r < 4; ++r) {
            const int gc = c0 + lkg * 4 + r;
            const float v0 = acc0[r];
            if (gc != row0 && v0 > minv[0]) {
                tv[0][minp[0]] = v0; ti[0][minp[0]] = gc;
                minv[0] = tv[0][0]; minp[0] = 0;
                #pragma unroll
                for (int j = 1; j < 8; ++j)
                    if (tv[0][j] < minv[0]) { minv[0] = tv[0][j]; minp[0] = j; }
            }
            const float v1 = acc1[r];
            if (gc != row1 && v1 > minv[1]) {
                tv[1][minp[1]] = v1; ti[1][minp[1]] = gc;
                minv[1] = tv[1][0]; minp[1] = 0;
                #pragma unroll
                for (int j = 1; j < 8; ++j)
                    if (tv[1][j] < minv[1]) { minv[1] = tv[1][j]; minp[1] = j; }
            }
        }
    }

    // ---- merge the 4 k-group sublists per row (padded LDS, once) ----
    __shared__ float smv[128 * 33];
    __shared__ int   smi[128 * 33];
    #pragma unroll
    for (int rs = 0; rs < 2; ++rs) {
        const int lr = wave * 32 + rs * 16 + lrow;
        #pragma unroll
        for (int j = 0; j < 8; ++j) {
            smv[lr * 33 + lkg * 8 + j] = tv[rs][j];
            smi[lr * 33 + lkg * 8 + j] = ti[rs][j];
        }
    }
    __syncthreads();
    if (t < 128) {
        float fv[8]; int fi[8];
        #pragma unroll
        for (int j = 0; j < 8; ++j) { fv[j] = -2.0f; fi[j] = 0; }
        float fmin = -2.0f; int fmp = 0;
        for (int c = 0; c < 32; ++c) {
            const float v = smv[t * 33 + c];
            const int   g = smi[t * 33 + c];
            if (v > fmin) {
                fv[fmp] = v; fi[fmp] = g;
                fmin = fv[0]; fmp = 0;
                #pragma unroll
                for (int j = 1; j < 8; ++j)
                    if (fv[j] < fmin) { fmin = fv[j]; fmp = j; }
            }
        }
        const size_t base = ((size_t)(b * NPTS + rb * 128 + t) * 4 + part) * 8;
        #pragma unroll
        for (int j = 0; j < 8; ++j) { ptv[base + j] = fv[j]; pti[base + j] = fi[j]; }
    }
}

// ---------------------------------------------------------------------------
// Merge 4 partial top-8 lists -> global top-8, softmax -> weights + indices.
// ---------------------------------------------------------------------------
__global__ __launch_bounds__(256)
void topk_merge(const float* __restrict__ ptv, const int* __restrict__ pti,
                float* __restrict__ tw, int* __restrict__ tidx) {
    const int row = blockIdx.x * 256 + threadIdx.x;
    float tv[8]; int ti[8];
    #pragma unroll
    for (int j = 0; j < 8; ++j) { tv[j] = -2.0f; ti[j] = 0; }
    float minv = -2.0f; int minp = 0;
    for (int c = 0; c < 32; ++c) {
        const float v = ptv[(size_t)row * 32 + c];
        const int   g = pti[(size_t)row * 32 + c];
        if (v > minv) {
            tv[minp] = v; ti[minp] = g;
            minv = tv[0]; minp = 0;
            #pragma unroll
            for (int j = 1; j < 8; ++j)
                if (tv[j] < minv) { minv = tv[j]; minp = j; }
        }
    }
    float m = tv[0];
    #pragma unroll
    for (int j = 1; j < 8; ++j) m = fmaxf(m, tv[j]);
    float e[8], Z = 0.0f;
    #pragma unroll
    for (int j = 0; j < 8; ++j) { e[j] = __expf(tv[j] - m); Z += e[j]; }
    const float inv = 1.0f / Z;
    #pragma unroll
    for (int j = 0; j < 8; ++j) {
        tw[(size_t)row * 8 + j]   = e[j] * inv;
        tidx[(size_t)row * 8 + j] = ti[j];
    }
}

// ---------------------------------------------------------------------------
// h <- LayerNorm(h[row] + sum_j w_j * V[idx_j])   (in-place over h)
// ---------------------------------------------------------------------------
__global__ __launch_bounds__(128)
void agg_ln(float* hio, const float* __restrict__ V,
            const int* __restrict__ tidx, const float* __restrict__ tw,
            const float* __restrict__ g, const float* __restrict__ be) {
    const int row = blockIdx.x;
    const int b   = row >> 12;
    const float* Vb = V + (size_t)b * NPTS * EMB;
    const int t = threadIdx.x;
    const int e = t * 4;
    float4 acc = *(const float4*)&hio[(size_t)row * EMB + e];
    #pragma unroll
    for (int j = 0; j < 8; ++j) {
        const int   idx = tidx[(size_t)row * 8 + j];
        const float w   = tw[(size_t)row * 8 + j];
        const float4 v  = *(const float4*)&Vb[(size_t)idx * EMB + e];
        acc.x = fmaf(w, v.x, acc.x);
        acc.y = fmaf(w, v.y, acc.y);
        acc.z = fmaf(w, v.z, acc.z);
        acc.w = fmaf(w, v.w, acc.w);
    }
    float s  = acc.x + acc.y + acc.z + acc.w;
    float ss = acc.x * acc.x + acc.y * acc.y + acc.z * acc.z + acc.w * acc.w;
    #pragma unroll
    for (int o = 32; o > 0; o >>= 1) { s += __shfl_xor(s, o); ss += __shfl_xor(ss, o); }
    __shared__ float red[4];
    if ((t & 63) == 0) { red[(t >> 6) * 2] = s; red[(t >> 6) * 2 + 1] = ss; }
    __syncthreads();
    s  = red[0] + red[2];
    ss = red[1] + red[3];
    const float mu   = s * (1.0f / EMB);
    const float var  = ss * (1.0f / EMB) - mu * mu;
    const float rstd = rsqrtf(var + 1e-5f);
    const float4 gg = *(const float4*)&g[e];
    const float4 bb = *(const float4*)&be[e];
    float4 o4;
    o4.x = (acc.x - mu) * rstd * gg.x + bb.x;
    o4.y = (acc.y - mu) * rstd * gg.y + bb.y;
    o4.z = (acc.z - mu) * rstd * gg.z + bb.z;
    o4.w = (acc.w - mu) * rstd * gg.w + bb.w;
    *(float4*)&hio[(size_t)row * EMB + e] = o4;
}

// ---------------------------------------------------------------------------
__global__ __launch_bounds__(256)
void score_kernel(const float* __restrict__ AV, const float* __restrict__ AU,
                  const float* __restrict__ aw_w, const float* __restrict__ aw_b,
                  float* __restrict__ score) {
    const int t    = threadIdx.x;
    const int row  = blockIdx.x * 4 + (t >> 6);
    const int lane = t & 63;
    float sum = 0.0f;
    #pragma unroll
    for (int i = 0; i < 2; ++i) {
        const int a = lane + i * 64;
        const float v = tanhf(AV[(size_t)row * ATT + a]);
        const float u = 1.0f / (1.0f + __expf(-AU[(size_t)row * ATT + a]));
        sum = fmaf(v * u, aw_w[a], sum);
    }
    #pragma unroll
    for (int o = 32; o > 0; o >>= 1) sum += __shfl_xor(sum, o);
    if (lane == 0) score[row] = sum + aw_b[0];
}

// ---------------------------------------------------------------------------
__global__ __launch_bounds__(256)
void softmax_kernel(const float* __restrict__ score, float* __restrict__ A,
                    float* __restrict__ bag) {
    const int b = blockIdx.x;
    const int t = threadIdx.x;
    const float* sb = score + b * NPTS;
    float loc[16];
    float m = -1e30f;
    #pragma unroll
    for (int i = 0; i < 16; ++i) { loc[i] = sb[t + i * 256]; m = fmaxf(m, loc[i]); }
    #pragma unroll
    for (int o = 32; o > 0; o >>= 1) m = fmaxf(m, __shfl_xor(m, o));
    __shared__ float redm[4];
    __shared__ float redz[4];
    if ((t & 63) == 0) redm[t >> 6] = m;
    __syncthreads();
    m = fmaxf(fmaxf(redm[0], redm[1]), fmaxf(redm[2], redm[3]));
    float Z = 0.0f;
    #pragma unroll
    for (int i = 0; i < 16; ++i) { loc[i] = __expf(loc[i] - m); Z += loc[i]; }
    #pragma unroll
    for (int o = 32; o > 0; o >>= 1) Z += __shfl_xor(Z, o);
    if ((t & 63) == 0) redz[t >> 6] = Z;
    __syncthreads();
    Z = redz[0] + redz[1] + redz[2] + redz[3];
    const float inv = 1.0f / Z;
    #pragma unroll
    for (int i = 0; i < 16; ++i) A[b * NPTS + t + i * 256] = loc[i] * inv;
    bag[b * EMB + t]       = 0.0f;
    bag[b * EMB + t + 256] = 0.0f;
}

// ---------------------------------------------------------------------------
__global__ __launch_bounds__(512)
void bagpart_kernel(const float* __restrict__ A, const float* __restrict__ h2,
                    float* __restrict__ bag) {
    const int b = blockIdx.y;
    const int s = blockIdx.x;
    const int e = threadIdx.x;
    const int n0 = s * 256;
    float acc = 0.0f;
    for (int n = 0; n < 256; ++n) {
        const float a = A[b * NPTS + n0 + n];
        acc = fmaf(a, h2[(size_t)(b * NPTS + n0 + n) * EMB + e], acc);
    }
    atomicAdd(&bag[b * EMB + e], acc);
}

// ---------------------------------------------------------------------------
__global__ __launch_bounds__(512)
void logits_kernel(const float* __restrict__ bag, const float* __restrict__ cls_w,
                   const float* __restrict__ cls_b, float* __restrict__ out) {
    const int t    = threadIdx.x;
    const int w    = t >> 6;
    const int lane = t & 63;
    const int b = w >> 1, c = w & 1;
    float sum = 0.0f;
    #pragma unroll
    for (int i = 0; i < 8; ++i) {
        const int e = lane + i * 64;
        sum = fmaf(bag[b * EMB + e], cls_w[e * NCLS + c], sum);
    }
    #pragma unroll
    for (int o = 32; o > 0; o >>= 1) sum += __shfl_xor(sum, o);
    if (lane == 0) out[b * NCLS + c] = sum + cls_b[c];
}

// ---------------------------------------------------------------------------
extern "C" void kernel_launch(void* const* d_in, const int* in_sizes, int n_in,
                              void* d_out, int out_size, void* d_ws, size_t ws_size,
                              hipStream_t stream) {
    const float* x     = (const float*)d_in[0];
    const float* pe_w  = (const float*)d_in[1];
    const float* pe_b  = (const float*)d_in[2];
    const float* wv_w  = (const float*)d_in[3];
    const float* wv_b  = (const float*)d_in[4];
    const float* ln_g  = (const float*)d_in[5];
    const float* ln_b  = (const float*)d_in[6];
    const float* av_w  = (const float*)d_in[7];
    const float* av_b  = (const float*)d_in[8];
    const float* au_w  = (const float*)d_in[9];
    const float* au_b  = (const float*)d_in[10];
    const float* aw_w  = (const float*)d_in[11];
    const float* aw_b  = (const float*)d_in[12];
    const float* cls_w = (const float*)d_in[13];
    const float* cls_b = (const float*)d_in[14];

    char* ws = (char*)d_ws;
    float*  h     = (float*)(ws + 0);
    ushort* hn    = (ushort*)(ws + 33554432);
    float*  V     = (float*)(ws + 33554432);
    float*  AV    = V;
    float*  AU    = (float*)(ws + 33554432 + 16777216);
    int*    tidx  = (int*)  (ws + 67108864);
    float*  tw    = (float*)(ws + 67633152);
    float*  scoreb= (float*)(ws + 68157440);
    float*  Asm   = (float*)(ws + 68222976);
    float*  bag   = (float*)(ws + 68288512);
    float*  ptv   = (float*)(ws + 68354048);
    int*    pti   = (int*)  (ws + 70451200);

    const int M = BATCH * NPTS;  // 16384

    // 1) h = x @ pe_w + pe_b
    gemm_bias<INDIM><<<dim3(EMB / 64, M / 64), dim3(256), 0, stream>>>(x, pe_w, pe_b, h, EMB);
    // 2) hn = bf16(normalize(h))
    normcast_kernel<<<dim3(M), dim3(64), 0, stream>>>(h, hn);
    // 3) MFMA cosine-sim + partial top-8  (barrier-free, 512 blocks)
    simtopk_mfma<<<dim3(512), dim3(256), 0, stream>>>(hn, ptv, pti);
    // 4) merge partials -> softmaxed weights + indices
    topk_merge<<<dim3(M / 256), dim3(256), 0, stream>>>(ptv, pti, tw, tidx);
    // 5) V = h @ wv_w + wv_b   (hn dead now; V overlays it)
    gemm_bias<EMB><<<dim3(EMB / 64, M / 64), dim3(256), 0, stream>>>(h, wv_w, wv_b, V, EMB);
    // 6) h <- LN(h + gather(V))
    agg_ln<<<dim3(M), dim3(128), 0, stream>>>(h, V, tidx, tw, ln_g, ln_b);
    // 7) AV/AU pre-activations
    gemm_bias<EMB><<<dim3(ATT / 64, M / 64), dim3(256), 0, stream>>>(h, av_w, av_b, AV, ATT);
    gemm_bias<EMB><<<dim3(ATT / 64, M / 64), dim3(256), 0, stream>>>(h, au_w, au_b, AU, ATT);
    // 8) gated-attention scores
    score_kernel<<<dim3(M / 4), dim3(256), 0, stream>>>(AV, AU, aw_w, aw_b, scoreb);
    // 9) per-batch softmax (+ zero bag)
    softmax_kernel<<<dim3(BATCH), dim3(256), 0, stream>>>(scoreb, Asm, bag);
    // 10) weighted pooling
    bagpart_kernel<<<dim3(16, BATCH), dim3(512), 0, stream>>>(Asm, h, bag);
    // 11) classifier
    logits_kernel<<<dim3(1), dim3(512), 0, stream>>>(bag, cls_w, cls_b, (float*)d_out);
}

// Round 11
// 877.282 us; speedup vs baseline: 2.1385x; 1.0008x over previous
//
#include <hip/hip_runtime.h>

#define BATCH 4
#define NPTS  4096
#define INDIM 1024
#define EMB   512
#define ATT   128
#define KNN   8
#define NCLS  2

typedef __attribute__((ext_vector_type(8))) short bf16x8;
typedef __attribute__((ext_vector_type(4))) float f32x4;

// ---------------------------------------------------------------------------
// Tiled fp32 GEMM:  C[M,Nc] = A[M,K] @ W[K,Nc] + bias[Nc]
// ---------------------------------------------------------------------------
template<int K>
__global__ __launch_bounds__(256)
void gemm_bias(const float* __restrict__ A, const float* __restrict__ W,
               const float* __restrict__ bias, float* __restrict__ C, int Nc) {
    __shared__ float As[16][68];
    __shared__ float Ws[16][68];
    const int r0 = blockIdx.y * 64;
    const int c0 = blockIdx.x * 64;
    const int t  = threadIdx.x;
    const int tx = t & 15, ty = t >> 4;
    const int lrow = t >> 2, lkc = (t & 3) * 4;
    const int wkk  = t >> 4, wcc = (t & 15) * 4;
    float acc[4][4] = {};
    for (int k0 = 0; k0 < K; k0 += 16) {
        const float4 a4 = *(const float4*)&A[(size_t)(r0 + lrow) * K + k0 + lkc];
        As[lkc + 0][lrow] = a4.x;
        As[lkc + 1][lrow] = a4.y;
        As[lkc + 2][lrow] = a4.z;
        As[lkc + 3][lrow] = a4.w;
        *(float4*)&Ws[wkk][wcc] = *(const float4*)&W[(size_t)(k0 + wkk) * Nc + c0 + wcc];
        __syncthreads();
        #pragma unroll
        for (int k = 0; k < 16; ++k) {
            const float4 a = *(const float4*)&As[k][ty * 4];
            const float4 b = *(const float4*)&Ws[k][tx * 4];
            const float a_[4] = {a.x, a.y, a.z, a.w};
            const float b_[4] = {b.x, b.y, b.z, b.w};
            #pragma unroll
            for (int i = 0; i < 4; ++i)
                #pragma unroll
                for (int j = 0; j < 4; ++j)
                    acc[i][j] = fmaf(a_[i], b_[j], acc[i][j]);
        }
        __syncthreads();
    }
    const float4 b4 = *(const float4*)&bias[c0 + tx * 4];
    #pragma unroll
    for (int i = 0; i < 4; ++i) {
        float4 o;
        o.x = acc[i][0] + b4.x;
        o.y = acc[i][1] + b4.y;
        o.z = acc[i][2] + b4.z;
        o.w = acc[i][3] + b4.w;
        *(float4*)&C[(size_t)(r0 + ty * 4 + i) * Nc + c0 + tx * 4] = o;
    }
}

// ---------------------------------------------------------------------------
// Normalize rows of h (fp32) -> hn (bf16).  One 64-thread block per row.
// ---------------------------------------------------------------------------
__device__ __forceinline__ ushort f2bf(float x) {
    unsigned u = __float_as_uint(x);
    u += 0x7fff + ((u >> 16) & 1);   // RNE
    return (ushort)(u >> 16);
}

__global__ __launch_bounds__(64)
void normcast_kernel(const float* __restrict__ h, ushort* __restrict__ hn) {
    const int row  = blockIdx.x;
    const int lane = threadIdx.x;
    const float4 v0 = *(const float4*)&h[(size_t)row * EMB + lane * 8];
    const float4 v1 = *(const float4*)&h[(size_t)row * EMB + lane * 8 + 4];
    float ss = v0.x * v0.x + v0.y * v0.y + v0.z * v0.z + v0.w * v0.w
             + v1.x * v1.x + v1.y * v1.y + v1.z * v1.z + v1.w * v1.w;
    #pragma unroll
    for (int o = 32; o > 0; o >>= 1) ss += __shfl_xor(ss, o);
    const float rn = 1.0f / fmaxf(sqrtf(ss), 1e-12f);
    uint4 o4;
    o4.x = (unsigned)f2bf(v0.x * rn) | ((unsigned)f2bf(v0.y * rn) << 16);
    o4.y = (unsigned)f2bf(v0.z * rn) | ((unsigned)f2bf(v0.w * rn) << 16);
    o4.z = (unsigned)f2bf(v1.x * rn) | ((unsigned)f2bf(v1.y * rn) << 16);
    o4.w = (unsigned)f2bf(v1.z * rn) | ((unsigned)f2bf(v1.w * rn) << 16);
    *(uint4*)&hn[(size_t)row * EMB + lane * 8] = o4;
}

// ---------------------------------------------------------------------------
// MFMA cosine-sim + running top-8, v4: barrier-free main loop + early-out.
//  - Swapped operands: mfma(col_frag, row_frag) -> lane-local top-8 scan.
//  - A (32 rows x K=512 per wave) in registers, loaded once.
//  - B col-fragments straight from global (L2-hot).
//  - 1024 blocks (8 parts x 512 cols): 4 blocks/CU -> occupancy cap 50%.
//  - Per-cf early-out: skip scan when max(candidates) <= running 8th-best.
// ---------------------------------------------------------------------------
__global__ __launch_bounds__(256, 2)
void simtopk_mfma(const ushort* __restrict__ hn,
                  float* __restrict__ ptv, int* __restrict__ pti) {
    const int orig = blockIdx.x;
    const int wg   = (orig & 7) * 128 + (orig >> 3);  // bijective: 1024 = 8*128
    const int b    = wg >> 8;          // batch (256 blocks each)
    const int part = (wg >> 5) & 7;    // 8 parts x 512 cols
    const int rb   = wg & 31;          // 32 row-blocks x 128 rows
    const ushort* hb = hn + (size_t)b * NPTS * EMB;

    const int t    = threadIdx.x;
    const int wave = t >> 6;
    const int lane = t & 63;
    const int lrow = lane & 15;        // operand dim index
    const int lkg  = lane >> 4;        // k-group

    const int rowbase = rb * 128 + wave * 32;

    // ---- A fragments (as MFMA B-operand): 2 rowsets x 16 rows, full K ----
    bf16x8 a_reg[2][16];
    #pragma unroll
    for (int rs = 0; rs < 2; ++rs) {
        const size_t abase = (size_t)(rowbase + rs * 16 + lrow) * EMB + lkg * 8;
        #pragma unroll
        for (int kk = 0; kk < 16; ++kk)
            a_reg[rs][kk] = *(const bf16x8*)&hb[abase + kk * 32];
    }

    float tv[2][8]; int ti[2][8];
    float minv[2]; int minp[2];
    #pragma unroll
    for (int rs = 0; rs < 2; ++rs) {
        minv[rs] = -2.0f; minp[rs] = 0;
        #pragma unroll
        for (int j = 0; j < 8; ++j) { tv[rs][j] = -2.0f; ti[rs][j] = 0; }
    }

    const int row0 = rowbase + lrow;
    const int row1 = rowbase + 16 + lrow;
    const int cpart = part * 512;

    for (int cf = 0; cf < 32; ++cf) {
        const int c0 = cpart + cf * 16;
        // col-fragment (as MFMA A-operand): 16 cols x full K
        bf16x8 bf[16];
        const size_t bbase = (size_t)(c0 + lrow) * EMB + lkg * 8;
        #pragma unroll
        for (int kk = 0; kk < 16; ++kk)
            bf[kk] = *(const bf16x8*)&hb[bbase + kk * 32];

        f32x4 acc0 = {0.f, 0.f, 0.f, 0.f};
        f32x4 acc1 = {0.f, 0.f, 0.f, 0.f};
        #pragma unroll
        for (int kk = 0; kk < 16; ++kk) {
            acc0 = __builtin_amdgcn_mfma_f32_16x16x32_bf16(bf[kk], a_reg[0][kk], acc0, 0, 0, 0);
            acc1 = __builtin_amdgcn_mfma_f32_16x16x32_bf16(bf[kk], a_reg[1][kk], acc1, 0, 0, 0);
        }

        // early-out per rowset: skip scan if no candidate beats the 8th-best
        const float m0 = fmaxf(fmaxf(acc0[0], acc0[1]), fmaxf(acc0[2], acc0[3]));
        if (m0 > minv[0]) {
            #pragma unroll
            for (int r = 0; r < 4; ++r) {
                const int gc = c0 + lkg * 4 + r;
                const float v0 = acc0[r];
                if (gc != row0 && v0 > minv[0]) {
                    tv[0][minp[0]] = v0; ti[0][minp[0]] = gc;
                    minv[0] = tv[0][0]; minp[0] = 0;
                    #pragma unroll
                    for (int j = 1; j < 8; ++j)
                        if (tv[0][j] < minv[0]) { minv[0] = tv[0][j]; minp[0] = j; }
                }
            }
        }
        const float m1 = fmaxf(fmaxf(acc1[0], acc1[1]), fmaxf(acc1[2], acc1[3]));
        if (m1 > minv[1]) {
            #pragma unroll
            for (int r = 0; r < 4; ++r) {
                const int gc = c0 + lkg * 4 + r;
                const float v1 = acc1[r];
                if (gc != row1 && v1 > minv[1]) {
                    tv[1][minp[1]] = v1; ti[1][minp[1]] = gc;
                    minv[1] = tv[1][0]; minp[1] = 0;
                    #pragma unroll
                    for (int j = 1; j < 8; ++j)
                        if (tv[1][j] < minv[1]) { minv[1] = tv[1][j]; minp[1] = j; }
                }
            }
        }
    }

    // ---- merge the 4 k-group sublists per row (padded LDS, once) ----
    __shared__ float smv[128 * 33];
    __shared__ int   smi[128 * 33];
    #pragma unroll
    for (int rs = 0; rs < 2; ++rs) {
        const int lr = wave * 32 + rs * 16 + lrow;
        #pragma unroll
        for (int j = 0; j < 8; ++j) {
            smv[lr * 33 + lkg * 8 + j] = tv[rs][j];
            smi[lr * 33 + lkg * 8 + j] = ti[rs][j];
        }
    }
    __syncthreads();
    if (t < 128) {
        float fv[8]; int fi[8];
        #pragma unroll
        for (int j = 0; j < 8; ++j) { fv[j] = -2.0f; fi[j] = 0; }
        float fmin = -2.0f; int fmp = 0;
        for (int c = 0; c < 32; ++c) {
            const float v = smv[t * 33 + c];
            const int   g = smi[t * 33 + c];
            if (v > fmin) {
                fv[fmp] = v; fi[fmp] = g;
                fmin = fv[0]; fmp = 0;
                #pragma unroll
                for (int j = 1; j < 8; ++j)
                    if (fv[j] < fmin) { fmin = fv[j]; fmp = j; }
            }
        }
        const size_t base = ((size_t)(b * NPTS + rb * 128 + t) * 8 + part) * 8;
        #pragma unroll
        for (int j = 0; j < 8; ++j) { ptv[base + j] = fv[j]; pti[base + j] = fi[j]; }
    }
}

// ---------------------------------------------------------------------------
// Merge 8 partial top-8 lists -> global top-8, softmax -> weights + indices.
// ---------------------------------------------------------------------------
__global__ __launch_bounds__(256)
void topk_merge(const float* __restrict__ ptv, const int* __restrict__ pti,
                float* __restrict__ tw, int* __restrict__ tidx) {
    const int row = blockIdx.x * 256 + threadIdx.x;
    float tv[8]; int ti[8];
    #pragma unroll
    for (int j = 0; j < 8; ++j) { tv[j] = -2.0f; ti[j] = 0; }
    float minv = -2.0f; int minp = 0;
    for (int c = 0; c < 64; ++c) {
        const float v = ptv[(size_t)row * 64 + c];
        const int   g = pti[(size_t)row * 64 + c];
        if (v > minv) {
            tv[minp] = v; ti[minp] = g;
            minv = tv[0]; minp = 0;
            #pragma unroll
            for (int j = 1; j < 8; ++j)
                if (tv[j] < minv) { minv = tv[j]; minp = j; }
        }
    }
    float m = tv[0];
    #pragma unroll
    for (int j = 1; j < 8; ++j) m = fmaxf(m, tv[j]);
    float e[8], Z = 0.0f;
    #pragma unroll
    for (int j = 0; j < 8; ++j) { e[j] = __expf(tv[j] - m); Z += e[j]; }
    const float inv = 1.0f / Z;
    #pragma unroll
    for (int j = 0; j < 8; ++j) {
        tw[(size_t)row * 8 + j]   = e[j] * inv;
        tidx[(size_t)row * 8 + j] = ti[j];
    }
}

// ---------------------------------------------------------------------------
// h <- LayerNorm(h[row] + sum_j w_j * V[idx_j])   (in-place over h)
// ---------------------------------------------------------------------------
__global__ __launch_bounds__(128)
void agg_ln(float* hio, const float* __restrict__ V,
            const int* __restrict__ tidx, const float* __restrict__ tw,
            const float* __restrict__ g, const float* __restrict__ be) {
    const int row = blockIdx.x;
    const int b   = row >> 12;
    const float* Vb = V + (size_t)b * NPTS * EMB;
    const int t = threadIdx.x;
    const int e = t * 4;
    float4 acc = *(const float4*)&hio[(size_t)row * EMB + e];
    #pragma unroll
    for (int j = 0; j < 8; ++j) {
        const int   idx = tidx[(size_t)row * 8 + j];
        const float w   = tw[(size_t)row * 8 + j];
        const float4 v  = *(const float4*)&Vb[(size_t)idx * EMB + e];
        acc.x = fmaf(w, v.x, acc.x);
        acc.y = fmaf(w, v.y, acc.y);
        acc.z = fmaf(w, v.z, acc.z);
        acc.w = fmaf(w, v.w, acc.w);
    }
    float s  = acc.x + acc.y + acc.z + acc.w;
    float ss = acc.x * acc.x + acc.y * acc.y + acc.z * acc.z + acc.w * acc.w;
    #pragma unroll
    for (int o = 32; o > 0; o >>= 1) { s += __shfl_xor(s, o); ss += __shfl_xor(ss, o); }
    __shared__ float red[4];
    if ((t & 63) == 0) { red[(t >> 6) * 2] = s; red[(t >> 6) * 2 + 1] = ss; }
    __syncthreads();
    s  = red[0] + red[2];
    ss = red[1] + red[3];
    const float mu   = s * (1.0f / EMB);
    const float var  = ss * (1.0f / EMB) - mu * mu;
    const float rstd = rsqrtf(var + 1e-5f);
    const float4 gg = *(const float4*)&g[e];
    const float4 bb = *(const float4*)&be[e];
    float4 o4;
    o4.x = (acc.x - mu) * rstd * gg.x + bb.x;
    o4.y = (acc.y - mu) * rstd * gg.y + bb.y;
    o4.z = (acc.z - mu) * rstd * gg.z + bb.z;
    o4.w = (acc.w - mu) * rstd * gg.w + bb.w;
    *(float4*)&hio[(size_t)row * EMB + e] = o4;
}

// ---------------------------------------------------------------------------
__global__ __launch_bounds__(256)
void score_kernel(const float* __restrict__ AV, const float* __restrict__ AU,
                  const float* __restrict__ aw_w, const float* __restrict__ aw_b,
                  float* __restrict__ score) {
    const int t    = threadIdx.x;
    const int row  = blockIdx.x * 4 + (t >> 6);
    const int lane = t & 63;
    float sum = 0.0f;
    #pragma unroll
    for (int i = 0; i < 2; ++i) {
        const int a = lane + i * 64;
        const float v = tanhf(AV[(size_t)row * ATT + a]);
        const float u = 1.0f / (1.0f + __expf(-AU[(size_t)row * ATT + a]));
        sum = fmaf(v * u, aw_w[a], sum);
    }
    #pragma unroll
    for (int o = 32; o > 0; o >>= 1) sum += __shfl_xor(sum, o);
    if (lane == 0) score[row] = sum + aw_b[0];
}

// ---------------------------------------------------------------------------
__global__ __launch_bounds__(256)
void softmax_kernel(const float* __restrict__ score, float* __restrict__ A,
                    float* __restrict__ bag) {
    const int b = blockIdx.x;
    const int t = threadIdx.x;
    const float* sb = score + b * NPTS;
    float loc[16];
    float m = -1e30f;
    #pragma unroll
    for (int i = 0; i < 16; ++i) { loc[i] = sb[t + i * 256]; m = fmaxf(m, loc[i]); }
    #pragma unroll
    for (int o = 32; o > 0; o >>= 1) m = fmaxf(m, __shfl_xor(m, o));
    __shared__ float redm[4];
    __shared__ float redz[4];
    if ((t & 63) == 0) redm[t >> 6] = m;
    __syncthreads();
    m = fmaxf(fmaxf(redm[0], redm[1]), fmaxf(redm[2], redm[3]));
    float Z = 0.0f;
    #pragma unroll
    for (int i = 0; i < 16; ++i) { loc[i] = __expf(loc[i] - m); Z += loc[i]; }
    #pragma unroll
    for (int o = 32; o > 0; o >>= 1) Z += __shfl_xor(Z, o);
    if ((t & 63) == 0) redz[t >> 6] = Z;
    __syncthreads();
    Z = redz[0] + redz[1] + redz[2] + redz[3];
    const float inv = 1.0f / Z;
    #pragma unroll
    for (int i = 0; i < 16; ++i) A[b * NPTS + t + i * 256] = loc[i] * inv;
    bag[b * EMB + t]       = 0.0f;
    bag[b * EMB + t + 256] = 0.0f;
}

// ---------------------------------------------------------------------------
__global__ __launch_bounds__(512)
void bagpart_kernel(const float* __restrict__ A, const float* __restrict__ h2,
                    float* __restrict__ bag) {
    const int b = blockIdx.y;
    const int s = blockIdx.x;
    const int e = threadIdx.x;
    const int n0 = s * 256;
    float acc = 0.0f;
    for (int n = 0; n < 256; ++n) {
        const float a = A[b * NPTS + n0 + n];
        acc = fmaf(a, h2[(size_t)(b * NPTS + n0 + n) * EMB + e], acc);
    }
    atomicAdd(&bag[b * EMB + e], acc);
}

// ---------------------------------------------------------------------------
__global__ __launch_bounds__(512)
void logits_kernel(const float* __restrict__ bag, const float* __restrict__ cls_w,
                   const float* __restrict__ cls_b, float* __restrict__ out) {
    const int t    = threadIdx.x;
    const int w    = t >> 6;
    const int lane = t & 63;
    const int b = w >> 1, c = w & 1;
    float sum = 0.0f;
    #pragma unroll
    for (int i = 0; i < 8; ++i) {
        const int e = lane + i * 64;
        sum = fmaf(bag[b * EMB + e], cls_w[e * NCLS + c], sum);
    }
    #pragma unroll
    for (int o = 32; o > 0; o >>= 1) sum += __shfl_xor(sum, o);
    if (lane == 0) out[b * NCLS + c] = sum + cls_b[c];
}

// ---------------------------------------------------------------------------
extern "C" void kernel_launch(void* const* d_in, const int* in_sizes, int n_in,
                              void* d_out, int out_size, void* d_ws, size_t ws_size,
                              hipStream_t stream) {
    const float* x     = (const float*)d_in[0];
    const float* pe_w  = (const float*)d_in[1];
    const float* pe_b  = (const float*)d_in[2];
    const float* wv_w  = (const float*)d_in[3];
    const float* wv_b  = (const float*)d_in[4];
    const float* ln_g  = (const float*)d_in[5];
    const float* ln_b  = (const float*)d_in[6];
    const float* av_w  = (const float*)d_in[7];
    const float* av_b  = (const float*)d_in[8];
    const float* au_w  = (const float*)d_in[9];
    const float* au_b  = (const float*)d_in[10];
    const float* aw_w  = (const float*)d_in[11];
    const float* aw_b  = (const float*)d_in[12];
    const float* cls_w = (const float*)d_in[13];
    const float* cls_b = (const float*)d_in[14];

    char* ws = (char*)d_ws;
    // Layout: h [0,32M). hn bf16 [32M,48M) (dead after simtopk; V fp32 overlays
    // [32M,64M) from step 5). AV=V start; AU at 48M. pti (4MB) overlays the AU
    // region (AU written at step 7, after merge consumed pti at step 4).
    // ptv (4MB) at tail; high-water 72548352 bytes (same as proven layout).
    float*  h     = (float*)(ws + 0);
    ushort* hn    = (ushort*)(ws + 33554432);
    float*  V     = (float*)(ws + 33554432);
    float*  AV    = V;
    float*  AU    = (float*)(ws + 50331648);
    int*    pti   = (int*)  (ws + 50331648);   // 4 MB, consumed before AU write
    int*    tidx  = (int*)  (ws + 67108864);
    float*  tw    = (float*)(ws + 67633152);
    float*  scoreb= (float*)(ws + 68157440);
    float*  Asm   = (float*)(ws + 68222976);
    float*  bag   = (float*)(ws + 68288512);
    float*  ptv   = (float*)(ws + 68354048);   // 4 MB -> ends 72548352

    const int M = BATCH * NPTS;  // 16384

    // 1) h = x @ pe_w + pe_b
    gemm_bias<INDIM><<<dim3(EMB / 64, M / 64), dim3(256), 0, stream>>>(x, pe_w, pe_b, h, EMB);
    // 2) hn = bf16(normalize(h))
    normcast_kernel<<<dim3(M), dim3(64), 0, stream>>>(h, hn);
    // 3) MFMA cosine-sim + partial top-8  (barrier-free, 1024 blocks)
    simtopk_mfma<<<dim3(1024), dim3(256), 0, stream>>>(hn, ptv, pti);
    // 4) merge partials -> softmaxed weights + indices
    topk_merge<<<dim3(M / 256), dim3(256), 0, stream>>>(ptv, pti, tw, tidx);
    // 5) V = h @ wv_w + wv_b   (hn dead now; V overlays it)
    gemm_bias<EMB><<<dim3(EMB / 64, M / 64), dim3(256), 0, stream>>>(h, wv_w, wv_b, V, EMB);
    // 6) h <- LN(h + gather(V))
    agg_ln<<<dim3(M), dim3(128), 0, stream>>>(h, V, tidx, tw, ln_g, ln_b);
    // 7) AV/AU pre-activations
    gemm_bias<EMB><<<dim3(ATT / 64, M / 64), dim3(256), 0, stream>>>(h, av_w, av_b, AV, ATT);
    gemm_bias<EMB><<<dim3(ATT / 64, M / 64), dim3(256), 0, stream>>>(h, au_w, au_b, AU, ATT);
    // 8) gated-attention scores
    score_kernel<<<dim3(M / 4), dim3(256), 0, stream>>>(AV, AU, aw_w, aw_b, scoreb);
    // 9) per-batch softmax (+ zero bag)
    softmax_kernel<<<dim3(BATCH), dim3(256), 0, stream>>>(scoreb, Asm, bag);
    // 10) weighted pooling
    bagpart_kernel<<<dim3(16, BATCH), dim3(512), 0, stream>>>(Asm, h, bag);
    // 11) classifier
    logits_kernel<<<dim3(1), dim3(512), 0, stream>>>(bag, cls_w, cls_b, (float*)d_out);
}

// Round 14
// 871.350 us; speedup vs baseline: 2.1530x; 1.0068x over previous
//
#include <hip/hip_runtime.h>

#define BATCH 4
#define NPTS  4096
#define INDIM 1024
#define EMB   512
#define ATT   128
#define KNN   8
#define NCLS  2

typedef __attribute__((ext_vector_type(8))) short bf16x8;
typedef __attribute__((ext_vector_type(4))) float f32x4;

// ---------------------------------------------------------------------------
// Tiled fp32 GEMM:  C[M,Nc] = A[M,K] @ W[K,Nc] + bias[Nc]
// ---------------------------------------------------------------------------
template<int K>
__global__ __launch_bounds__(256)
void gemm_bias(const float* __restrict__ A, const float* __restrict__ W,
               const float* __restrict__ bias, float* __restrict__ C, int Nc) {
    __shared__ float As[16][68];
    __shared__ float Ws[16][68];
    const int r0 = blockIdx.y * 64;
    const int c0 = blockIdx.x * 64;
    const int t  = threadIdx.x;
    const int tx = t & 15, ty = t >> 4;
    const int lrow = t >> 2, lkc = (t & 3) * 4;
    const int wkk  = t >> 4, wcc = (t & 15) * 4;
    float acc[4][4] = {};
    for (int k0 = 0; k0 < K; k0 += 16) {
        const float4 a4 = *(const float4*)&A[(size_t)(r0 + lrow) * K + k0 + lkc];
        As[lkc + 0][lrow] = a4.x;
        As[lkc + 1][lrow] = a4.y;
        As[lkc + 2][lrow] = a4.z;
        As[lkc + 3][lrow] = a4.w;
        *(float4*)&Ws[wkk][wcc] = *(const float4*)&W[(size_t)(k0 + wkk) * Nc + c0 + wcc];
        __syncthreads();
        #pragma unroll
        for (int k = 0; k < 16; ++k) {
            const float4 a = *(const float4*)&As[k][ty * 4];
            const float4 b = *(const float4*)&Ws[k][tx * 4];
            const float a_[4] = {a.x, a.y, a.z, a.w};
            const float b_[4] = {b.x, b.y, b.z, b.w};
            #pragma unroll
            for (int i = 0; i < 4; ++i)
                #pragma unroll
                for (int j = 0; j < 4; ++j)
                    acc[i][j] = fmaf(a_[i], b_[j], acc[i][j]);
        }
        __syncthreads();
    }
    const float4 b4 = *(const float4*)&bias[c0 + tx * 4];
    #pragma unroll
    for (int i = 0; i < 4; ++i) {
        float4 o;
        o.x = acc[i][0] + b4.x;
        o.y = acc[i][1] + b4.y;
        o.z = acc[i][2] + b4.z;
        o.w = acc[i][3] + b4.w;
        *(float4*)&C[(size_t)(r0 + ty * 4 + i) * Nc + c0 + tx * 4] = o;
    }
}

// ---------------------------------------------------------------------------
// Normalize rows of h (fp32) -> hn (bf16).  One 64-thread block per row.
// ---------------------------------------------------------------------------
__device__ __forceinline__ ushort f2bf(float x) {
    unsigned u = __float_as_uint(x);
    u += 0x7fff + ((u >> 16) & 1);   // RNE
    return (ushort)(u >> 16);
}

__global__ __launch_bounds__(64)
void normcast_kernel(const float* __restrict__ h, ushort* __restrict__ hn) {
    const int row  = blockIdx.x;
    const int lane = threadIdx.x;
    const float4 v0 = *(const float4*)&h[(size_t)row * EMB + lane * 8];
    const float4 v1 = *(const float4*)&h[(size_t)row * EMB + lane * 8 + 4];
    float ss = v0.x * v0.x + v0.y * v0.y + v0.z * v0.z + v0.w * v0.w
             + v1.x * v1.x + v1.y * v1.y + v1.z * v1.z + v1.w * v1.w;
    #pragma unroll
    for (int o = 32; o > 0; o >>= 1) ss += __shfl_xor(ss, o);
    const float rn = 1.0f / fmaxf(sqrtf(ss), 1e-12f);
    uint4 o4;
    o4.x = (unsigned)f2bf(v0.x * rn) | ((unsigned)f2bf(v0.y * rn) << 16);
    o4.y = (unsigned)f2bf(v0.z * rn) | ((unsigned)f2bf(v0.w * rn) << 16);
    o4.z = (unsigned)f2bf(v1.x * rn) | ((unsigned)f2bf(v1.y * rn) << 16);
    o4.w = (unsigned)f2bf(v1.z * rn) | ((unsigned)f2bf(v1.w * rn) << 16);
    *(uint4*)&hn[(size_t)row * EMB + lane * 8] = o4;
}

// ---------------------------------------------------------------------------
// MFMA cosine-sim + running top-8, v5: register-resident A + dbuf B-frags.
//  - launch_bounds(256,1): ~300 VGPR budget so a_reg[2][16] stays resident
//    (v4's 96-VGPR budget forced per-cf reloads of A from global).
//  - Double-buffered bfA/bfB: next col-frag loads issue before MFMA chain.
//  - Swapped operands -> lane-local top-8 scan, no main-loop LDS/barriers.
//  - 512 blocks (4 parts x 1024 cols), bijective XCD swizzle.
// ---------------------------------------------------------------------------
__global__ __launch_bounds__(256, 1)
void simtopk_mfma(const ushort* __restrict__ hn,
                  float* __restrict__ ptv, int* __restrict__ pti) {
    const int orig = blockIdx.x;
    const int wg   = (orig & 7) * 64 + (orig >> 3);   // bijective: 512 = 8*64
    const int b    = wg >> 7;          // batch (128 blocks each)
    const int part = (wg >> 5) & 3;    // 4 parts x 1024 cols
    const int rb   = wg & 31;          // 32 row-blocks x 128 rows
    const ushort* hb = hn + (size_t)b * NPTS * EMB;

    const int t    = threadIdx.x;
    const int wave = t >> 6;
    const int lane = t & 63;
    const int lrow = lane & 15;        // operand dim index
    const int lkg  = lane >> 4;        // k-group

    const int rowbase = rb * 128 + wave * 32;

    // ---- A fragments (as MFMA B-operand): 2 rowsets x 16 rows, full K ----
    bf16x8 a_reg[2][16];
    #pragma unroll
    for (int rs = 0; rs < 2; ++rs) {
        const size_t abase = (size_t)(rowbase + rs * 16 + lrow) * EMB + lkg * 8;
        #pragma unroll
        for (int kk = 0; kk < 16; ++kk)
            a_reg[rs][kk] = *(const bf16x8*)&hb[abase + kk * 32];
    }

    float tv[2][8]; int ti[2][8];
    float minv[2]; int minp[2];
    #pragma unroll
    for (int rs = 0; rs < 2; ++rs) {
        minv[rs] = -2.0f; minp[rs] = 0;
        #pragma unroll
        for (int j = 0; j < 8; ++j) { tv[rs][j] = -2.0f; ti[rs][j] = 0; }
    }

    const int row0 = rowbase + lrow;
    const int row1 = rowbase + 16 + lrow;
    const int cpart = part * 1024;

    bf16x8 bfA[16], bfB[16];

    #define LOADB(dst, c0v)                                                   \
        { const size_t bb_ = (size_t)((c0v) + lrow) * EMB + lkg * 8;          \
          _Pragma("unroll")                                                   \
          for (int kk = 0; kk < 16; ++kk)                                     \
              dst[kk] = *(const bf16x8*)&hb[bb_ + kk * 32]; }

    #define COMPUTE(buf, c0v)                                                 \
        { f32x4 acc0 = {0.f, 0.f, 0.f, 0.f};                                  \
          f32x4 acc1 = {0.f, 0.f, 0.f, 0.f};                                  \
          _Pragma("unroll")                                                   \
          for (int kk = 0; kk < 16; ++kk) {                                   \
              acc0 = __builtin_amdgcn_mfma_f32_16x16x32_bf16(buf[kk], a_reg[0][kk], acc0, 0, 0, 0); \
              acc1 = __builtin_amdgcn_mfma_f32_16x16x32_bf16(buf[kk], a_reg[1][kk], acc1, 0, 0, 0); \
          }                                                                   \
          const float m0_ = fmaxf(fmaxf(acc0[0], acc0[1]), fmaxf(acc0[2], acc0[3])); \
          if (m0_ > minv[0]) {                                                \
              _Pragma("unroll")                                               \
              for (int r = 0; r < 4; ++r) {                                   \
                  const int gc = (c0v) + lkg * 4 + r;                         \
                  const float v0_ = acc0[r];                                  \
                  if (gc != row0 && v0_ > minv[0]) {                          \
                      tv[0][minp[0]] = v0_; ti[0][minp[0]] = gc;              \
                      minv[0] = tv[0][0]; minp[0] = 0;                        \
                      _Pragma("unroll")                                       \
                      for (int j = 1; j < 8; ++j)                             \
                          if (tv[0][j] < minv[0]) { minv[0] = tv[0][j]; minp[0] = j; } \
                  }                                                           \
              }                                                               \
          }                                                                   \
          const float m1_ = fmaxf(fmaxf(acc1[0], acc1[1]), fmaxf(acc1[2], acc1[3])); \
          if (m1_ > minv[1]) {                                                \
              _Pragma("unroll")                                               \
              for (int r = 0; r < 4; ++r) {                                   \
                  const int gc = (c0v) + lkg * 4 + r;                         \
                  const float v1_ = acc1[r];                                  \
                  if (gc != row1 && v1_ > minv[1]) {                          \
                      tv[1][minp[1]] = v1_; ti[1][minp[1]] = gc;              \
                      minv[1] = tv[1][0]; minp[1] = 0;                        \
                      _Pragma("unroll")                                       \
                      for (int j = 1; j < 8; ++j)                             \
                          if (tv[1][j] < minv[1]) { minv[1] = tv[1][j]; minp[1] = j; } \
                  }                                                           \
              }                                                               \
          }                                                                   \
        }

    LOADB(bfA, cpart)
    for (int cf = 0; cf < 64; cf += 2) {
        const int c0A = cpart + cf * 16;
        const int c0B = cpart + (cf + 1) * 16;
        LOADB(bfB, c0B)
        COMPUTE(bfA, c0A)
        if (cf + 2 < 64) { LOADB(bfA, cpart + (cf + 2) * 16) }
        COMPUTE(bfB, c0B)
    }
    #undef LOADB
    #undef COMPUTE

    // ---- merge the 4 k-group sublists per row (padded LDS, once) ----
    __shared__ float smv[128 * 33];
    __shared__ int   smi[128 * 33];
    #pragma unroll
    for (int rs = 0; rs < 2; ++rs) {
        const int lr = wave * 32 + rs * 16 + lrow;
        #pragma unroll
        for (int j = 0; j < 8; ++j) {
            smv[lr * 33 + lkg * 8 + j] = tv[rs][j];
            smi[lr * 33 + lkg * 8 + j] = ti[rs][j];
        }
    }
    __syncthreads();
    if (t < 128) {
        float fv[8]; int fi[8];
        #pragma unroll
        for (int j = 0; j < 8; ++j) { fv[j] = -2.0f; fi[j] = 0; }
        float fmin = -2.0f; int fmp = 0;
        for (int c = 0; c < 32; ++c) {
            const float v = smv[t * 33 + c];
            const int   g = smi[t * 33 + c];
            if (v > fmin) {
                fv[fmp] = v; fi[fmp] = g;
                fmin = fv[0]; fmp = 0;
                #pragma unroll
                for (int j = 1; j < 8; ++j)
                    if (fv[j] < fmin) { fmin = fv[j]; fmp = j; }
            }
        }
        const size_t base = ((size_t)(b * NPTS + rb * 128 + t) * 4 + part) * 8;
        #pragma unroll
        for (int j = 0; j < 8; ++j) { ptv[base + j] = fv[j]; pti[base + j] = fi[j]; }
    }
}

// ---------------------------------------------------------------------------
// Merge 4 partial top-8 lists -> global top-8, softmax -> weights + indices.
// ---------------------------------------------------------------------------
__global__ __launch_bounds__(256)
void topk_merge(const float* __restrict__ ptv, const int* __restrict__ pti,
                float* __restrict__ tw, int* __restrict__ tidx) {
    const int row = blockIdx.x * 256 + threadIdx.x;
    float tv[8]; int ti[8];
    #pragma unroll
    for (int j = 0; j < 8; ++j) { tv[j] = -2.0f; ti[j] = 0; }
    float minv = -2.0f; int minp = 0;
    for (int c = 0; c < 32; ++c) {
        const float v = ptv[(size_t)row * 32 + c];
        const int   g = pti[(size_t)row * 32 + c];
        if (v > minv) {
            tv[minp] = v; ti[minp] = g;
            minv = tv[0]; minp = 0;
            #pragma unroll
            for (int j = 1; j < 8; ++j)
                if (tv[j] < minv) { minv = tv[j]; minp = j; }
        }
    }
    float m = tv[0];
    #pragma unroll
    for (int j = 1; j < 8; ++j) m = fmaxf(m, tv[j]);
    float e[8], Z = 0.0f;
    #pragma unroll
    for (int j = 0; j < 8; ++j) { e[j] = __expf(tv[j] - m); Z += e[j]; }
    const float inv = 1.0f / Z;
    #pragma unroll
    for (int j = 0; j < 8; ++j) {
        tw[(size_t)row * 8 + j]   = e[j] * inv;
        tidx[(size_t)row * 8 + j] = ti[j];
    }
}

// ---------------------------------------------------------------------------
// h <- LayerNorm(h[row] + sum_j w_j * V[idx_j])   (in-place over h)
// ---------------------------------------------------------------------------
__global__ __launch_bounds__(128)
void agg_ln(float* hio, const float* __restrict__ V,
            const int* __restrict__ tidx, const float* __restrict__ tw,
            const float* __restrict__ g, const float* __restrict__ be) {
    const int row = blockIdx.x;
    const int b   = row >> 12;
    const float* Vb = V + (size_t)b * NPTS * EMB;
    const int t = threadIdx.x;
    const int e = t * 4;
    float4 acc = *(const float4*)&hio[(size_t)row * EMB + e];
    #pragma unroll
    for (int j = 0; j < 8; ++j) {
        const int   idx = tidx[(size_t)row * 8 + j];
        const float w   = tw[(size_t)row * 8 + j];
        const float4 v  = *(const float4*)&Vb[(size_t)idx * EMB + e];
        acc.x = fmaf(w, v.x, acc.x);
        acc.y = fmaf(w, v.y, acc.y);
        acc.z = fmaf(w, v.z, acc.z);
        acc.w = fmaf(w, v.w, acc.w);
    }
    float s  = acc.x + acc.y + acc.z + acc.w;
    float ss = acc.x * acc.x + acc.y * acc.y + acc.z * acc.z + acc.w * acc.w;
    #pragma unroll
    for (int o = 32; o > 0; o >>= 1) { s += __shfl_xor(s, o); ss += __shfl_xor(ss, o); }
    __shared__ float red[4];
    if ((t & 63) == 0) { red[(t >> 6) * 2] = s; red[(t >> 6) * 2 + 1] = ss; }
    __syncthreads();
    s  = red[0] + red[2];
    ss = red[1] + red[3];
    const float mu   = s * (1.0f / EMB);
    const float var  = ss * (1.0f / EMB) - mu * mu;
    const float rstd = rsqrtf(var + 1e-5f);
    const float4 gg = *(const float4*)&g[e];
    const float4 bb = *(const float4*)&be[e];
    float4 o4;
    o4.x = (acc.x - mu) * rstd * gg.x + bb.x;
    o4.y = (acc.y - mu) * rstd * gg.y + bb.y;
    o4.z = (acc.z - mu) * rstd * gg.z + bb.z;
    o4.w = (acc.w - mu) * rstd * gg.w + bb.w;
    *(float4*)&hio[(size_t)row * EMB + e] = o4;
}

// ---------------------------------------------------------------------------
__global__ __launch_bounds__(256)
void score_kernel(const float* __restrict__ AV, const float* __restrict__ AU,
                  const float* __restrict__ aw_w, const float* __restrict__ aw_b,
                  float* __restrict__ score) {
    const int t    = threadIdx.x;
    const int row  = blockIdx.x * 4 + (t >> 6);
    const int lane = t & 63;
    float sum = 0.0f;
    #pragma unroll
    for (int i = 0; i < 2; ++i) {
        const int a = lane + i * 64;
        const float v = tanhf(AV[(size_t)row * ATT + a]);
        const float u = 1.0f / (1.0f + __expf(-AU[(size_t)row * ATT + a]));
        sum = fmaf(v * u, aw_w[a], sum);
    }
    #pragma unroll
    for (int o = 32; o > 0; o >>= 1) sum += __shfl_xor(sum, o);
    if (lane == 0) score[row] = sum + aw_b[0];
}

// ---------------------------------------------------------------------------
__global__ __launch_bounds__(256)
void softmax_kernel(const float* __restrict__ score, float* __restrict__ A,
                    float* __restrict__ bag) {
    const int b = blockIdx.x;
    const int t = threadIdx.x;
    const float* sb = score + b * NPTS;
    float loc[16];
    float m = -1e30f;
    #pragma unroll
    for (int i = 0; i < 16; ++i) { loc[i] = sb[t + i * 256]; m = fmaxf(m, loc[i]); }
    #pragma unroll
    for (int o = 32; o > 0; o >>= 1) m = fmaxf(m, __shfl_xor(m, o));
    __shared__ float redm[4];
    __shared__ float redz[4];
    if ((t & 63) == 0) redm[t >> 6] = m;
    __syncthreads();
    m = fmaxf(fmaxf(redm[0], redm[1]), fmaxf(redm[2], redm[3]));
    float Z = 0.0f;
    #pragma unroll
    for (int i = 0; i < 16; ++i) { loc[i] = __expf(loc[i] - m); Z += loc[i]; }
    #pragma unroll
    for (int o = 32; o > 0; o >>= 1) Z += __shfl_xor(Z, o);
    if ((t & 63) == 0) redz[t >> 6] = Z;
    __syncthreads();
    Z = redz[0] + redz[1] + redz[2] + redz[3];
    const float inv = 1.0f / Z;
    #pragma unroll
    for (int i = 0; i < 16; ++i) A[b * NPTS + t + i * 256] = loc[i] * inv;
    bag[b * EMB + t]       = 0.0f;
    bag[b * EMB + t + 256] = 0.0f;
}

// ---------------------------------------------------------------------------
__global__ __launch_bounds__(512)
void bagpart_kernel(const float* __restrict__ A, const float* __restrict__ h2,
                    float* __restrict__ bag) {
    const int b = blockIdx.y;
    const int s = blockIdx.x;
    const int e = threadIdx.x;
    const int n0 = s * 256;
    float acc = 0.0f;
    for (int n = 0; n < 256; ++n) {
        const float a = A[b * NPTS + n0 + n];
        acc = fmaf(a, h2[(size_t)(b * NPTS + n0 + n) * EMB + e], acc);
    }
    atomicAdd(&bag[b * EMB + e], acc);
}

// ---------------------------------------------------------------------------
__global__ __launch_bounds__(512)
void logits_kernel(const float* __restrict__ bag, const float* __restrict__ cls_w,
                   const float* __restrict__ cls_b, float* __restrict__ out) {
    const int t    = threadIdx.x;
    const int w    = t >> 6;
    const int lane = t & 63;
    const int b = w >> 1, c = w & 1;
    float sum = 0.0f;
    #pragma unroll
    for (int i = 0; i < 8; ++i) {
        const int e = lane + i * 64;
        sum = fmaf(bag[b * EMB + e], cls_w[e * NCLS + c], sum);
    }
    #pragma unroll
    for (int o = 32; o > 0; o >>= 1) sum += __shfl_xor(sum, o);
    if (lane == 0) out[b * NCLS + c] = sum + cls_b[c];
}

// ---------------------------------------------------------------------------
extern "C" void kernel_launch(void* const* d_in, const int* in_sizes, int n_in,
                              void* d_out, int out_size, void* d_ws, size_t ws_size,
                              hipStream_t stream) {
    const float* x     = (const float*)d_in[0];
    const float* pe_w  = (const float*)d_in[1];
    const float* pe_b  = (const float*)d_in[2];
    const float* wv_w  = (const float*)d_in[3];
    const float* wv_b  = (const float*)d_in[4];
    const float* ln_g  = (const float*)d_in[5];
    const float* ln_b  = (const float*)d_in[6];
    const float* av_w  = (const float*)d_in[7];
    const float* av_b  = (const float*)d_in[8];
    const float* au_w  = (const float*)d_in[9];
    const float* au_b  = (const float*)d_in[10];
    const float* aw_w  = (const float*)d_in[11];
    const float* aw_b  = (const float*)d_in[12];
    const float* cls_w = (const float*)d_in[13];
    const float* cls_b = (const float*)d_in[14];

    char* ws = (char*)d_ws;
    // h [0,32M). hn bf16 [32M,48M) (dead after simtopk; V fp32 overlays
    // [32M,64M) from step 5). AV=V; AU at 48M. pti (2MB) overlays the AU
    // region (consumed at step 4, before AU written at step 7). ptv (2MB)
    // at tail; high-water 70451200 bytes.
    float*  h     = (float*)(ws + 0);
    ushort* hn    = (ushort*)(ws + 33554432);
    float*  V     = (float*)(ws + 33554432);
    float*  AV    = V;
    float*  AU    = (float*)(ws + 50331648);
    int*    pti   = (int*)  (ws + 50331648);   // 2 MB, consumed before AU write
    int*    tidx  = (int*)  (ws + 67108864);
    float*  tw    = (float*)(ws + 67633152);
    float*  scoreb= (float*)(ws + 68157440);
    float*  Asm   = (float*)(ws + 68222976);
    float*  bag   = (float*)(ws + 68288512);
    float*  ptv   = (float*)(ws + 68354048);   // 2 MB -> ends 70451200

    const int M = BATCH * NPTS;  // 16384

    // 1) h = x @ pe_w + pe_b
    gemm_bias<INDIM><<<dim3(EMB / 64, M / 64), dim3(256), 0, stream>>>(x, pe_w, pe_b, h, EMB);
    // 2) hn = bf16(normalize(h))
    normcast_kernel<<<dim3(M), dim3(64), 0, stream>>>(h, hn);
    // 3) MFMA cosine-sim + partial top-8  (barrier-free, 512 blocks)
    simtopk_mfma<<<dim3(512), dim3(256), 0, stream>>>(hn, ptv, pti);
    // 4) merge partials -> softmaxed weights + indices
    topk_merge<<<dim3(M / 256), dim3(256), 0, stream>>>(ptv, pti, tw, tidx);
    // 5) V = h @ wv_w + wv_b   (hn dead now; V overlays it)
    gemm_bias<EMB><<<dim3(EMB / 64, M / 64), dim3(256), 0, stream>>>(h, wv_w, wv_b, V, EMB);
    // 6) h <- LN(h + gather(V))
    agg_ln<<<dim3(M), dim3(128), 0, stream>>>(h, V, tidx, tw, ln_g, ln_b);
    // 7) AV/AU pre-activations
    gemm_bias<EMB><<<dim3(ATT / 64, M / 64), dim3(256), 0, stream>>>(h, av_w, av_b, AV, ATT);
    gemm_bias<EMB><<<dim3(ATT / 64, M / 64), dim3(256), 0, stream>>>(h, au_w, au_b, AU, ATT);
    // 8) gated-attention scores
    score_kernel<<<dim3(M / 4), dim3(256), 0, stream>>>(AV, AU, aw_w, aw_b, scoreb);
    // 9) per-batch softmax (+ zero bag)
    softmax_kernel<<<dim3(BATCH), dim3(256), 0, stream>>>(scoreb, Asm, bag);
    // 10) weighted pooling
    bagpart_kernel<<<dim3(16, BATCH), dim3(512), 0, stream>>>(Asm, h, bag);
    // 11) classifier
    logits_kernel<<<dim3(1), dim3(512), 0, stream>>>(bag, cls_w, cls_b, (float*)d_out);
}